// Round 1
// baseline (435.185 us; speedup 1.0000x reference)
//
#include <hip/hip_runtime.h>
#include <math.h>

typedef unsigned short u16;
typedef __attribute__((ext_vector_type(4))) float f32x4;
typedef __bf16 bf16x8 __attribute__((ext_vector_type(8)));

#define NTOK 8192
#define DDIM 1024
#define NEXP 7
#define CAPC 2574      /* int(8192*2/7*1.1) */
#define CPAD 2688      /* 21*128 */
#define MBE8 11        /* ceil(2688/256) */
#define EB8 (NEXP * MBE8 * 4)   /* 308 expert blocks (256x256 tiles, 4 n-blocks) */
#define TB8 (EB8 + 32 * 4)      /* + 128 shared blocks = 436 */

__device__ inline float bf2f(u16 u) {
    union { unsigned int i; float f; } c; c.i = ((unsigned int)u) << 16; return c.f;
}
__device__ inline u16 f2bf(float f) {
    union { float f; unsigned int i; } c; c.f = f;
    unsigned int u = c.i;
    unsigned int r = (u + 0x7fffu + ((u >> 16) & 1u)) >> 16;
    return (u16)r;
}

__device__ inline void gl2lds16(const u16* g, const u16* l) {
    __builtin_amdgcn_global_load_lds(
        (const __attribute__((address_space(1))) unsigned int*)g,
        (__attribute__((address_space(3))) unsigned int*)l, 16, 0, 0);
}

#define BAR()    asm volatile("s_barrier" ::: "memory")
#define WAITV0() asm volatile("s_waitcnt vmcnt(0)" ::: "memory")

// ---------------- guard: zero the output (ws_size-too-small diagnostic) ----------------
__global__ void k_zero(float* out, long n) {
    long i = (long)blockIdx.x * 256 + threadIdx.x;
    long stride = (long)gridDim.x * 256;
    for (; i < n; i += stride) out[i] = 0.f;
}

// ---------------- fused prep ----------------
// blocks 0..4095: x->bf16 + inits; 4096..8191: transpose W1/Ws1 -> Wt/Wst;
// 8192..12287 (only when sep): transpose W2/Ws2 -> Wt2/Wst2.
__global__ void k_prep(const float* __restrict__ x, u16* __restrict__ xb,
                       int* __restrict__ slot_token, u16* __restrict__ zrow,
                       const float* __restrict__ W1, const float* __restrict__ Ws1,
                       u16* __restrict__ Wt, u16* __restrict__ Wst,
                       const float* __restrict__ W2, const float* __restrict__ Ws2,
                       u16* __restrict__ Wt2, u16* __restrict__ Wst2) {
    int bid = blockIdx.x, tid = threadIdx.x;
    if (bid < 4096) {
        int gid = bid * 256 + tid;
        int i = gid * 8;
        float4 a = *(const float4*)(x + i);
        float4 b = *(const float4*)(x + i + 4);
        ushort4 o0; o0.x = f2bf(a.x); o0.y = f2bf(a.y); o0.z = f2bf(a.z); o0.w = f2bf(a.w);
        ushort4 o1; o1.x = f2bf(b.x); o1.y = f2bf(b.y); o1.z = f2bf(b.z); o1.w = f2bf(b.w);
        *(ushort4*)(xb + i) = o0;
        *(ushort4*)(xb + i + 4) = o1;
        if (gid < DDIM) zrow[gid] = 0;
        if (gid < NEXP * CPAD + 128) slot_token[gid] = NTOK;   /* +128 pad for 256-row tile over-read */
        return;
    }
    int phase2 = (bid >= 8192);
    int tb = bid - (phase2 ? 8192 : 4096);
    const float* srcE = phase2 ? W2 : W1;
    const float* srcS = phase2 ? Ws2 : Ws1;
    u16* dE = phase2 ? Wt2 : Wt;
    u16* dS = phase2 ? Wst2 : Wst;
    int z = tb >> 9; int rem = tb & 511;
    int y = rem >> 2; int xq = rem & 3;
    const float* src; u16* dst;
    if (z < 7) { src = srcE + (long)z * 1048576; dst = dE + (long)z * 1048576; }
    else       { src = srcS;                     dst = dS; }
    int n = xq * 256 + tid;
    int k0 = y * 8;
    u16 v[8];
#pragma unroll
    for (int j = 0; j < 8; ++j) v[j] = f2bf(src[(long)(k0 + j) * 1024 + n]);
    ushort4 a; a.x = v[0]; a.y = v[1]; a.z = v[2]; a.w = v[3];
    ushort4 b; b.x = v[4]; b.y = v[5]; b.z = v[6]; b.w = v[7];
    *(ushort4*)(dst + (long)n * 1024 + k0) = a;
    *(ushort4*)(dst + (long)n * 1024 + k0 + 4) = b;
}

// ---------------- weight transpose phase 2 (fallback when !sep) ----------------
__global__ void k_transpose(const float* __restrict__ srcE, const float* __restrict__ srcS,
                            u16* __restrict__ Wt, u16* __restrict__ Wst) {
    int z = blockIdx.z;
    const float* src; u16* dst;
    if (z < 7) { src = srcE + (long)z * 1048576; dst = Wt + (long)z * 1048576; }
    else       { src = srcS;                     dst = Wst; }
    int n = blockIdx.x * 256 + threadIdx.x;
    int k0 = blockIdx.y * 8;
    u16 v[8];
#pragma unroll
    for (int j = 0; j < 8; ++j) v[j] = f2bf(src[(long)(k0 + j) * 1024 + n]);
    ushort4 a; a.x = v[0]; a.y = v[1]; a.z = v[2]; a.w = v[3];
    ushort4 b; b.x = v[4]; b.y = v[5]; b.z = v[6]; b.w = v[7];
    *(ushort4*)(dst + (long)n * 1024 + k0) = a;
    *(ushort4*)(dst + (long)n * 1024 + k0 + 4) = b;
}

// ---------------- router main: fp64 dot-products only (no libm -> low VGPR) ----------------
__global__ __launch_bounds__(512) void k_router(
    const float* __restrict__ x,
    const float* __restrict__ Wr, const float* __restrict__ Wn,
    double* __restrict__ arO, double* __restrict__ anO) {
    __shared__ float swr[7168];
    __shared__ float swn[7168];
    int tid = threadIdx.x;
    for (int i = tid; i < 7168; i += 512) { swr[i] = Wr[i]; swn[i] = Wn[i]; }
    __syncthreads();
    int lane = tid & 63, wv = tid >> 6;
    int t = blockIdx.x * 8 + wv;
    double ar[7] = {0,0,0,0,0,0,0}, an[7] = {0,0,0,0,0,0,0};
    for (int j = 0; j < 16; ++j) {
        int d = j * 64 + lane;
        double xd = (double)x[t * 1024 + d];
#pragma unroll
        for (int e = 0; e < 7; ++e) {
            ar[e] += xd * (double)swr[d * 7 + e];
            an[e] += xd * (double)swn[d * 7 + e];
        }
    }
#pragma unroll
    for (int e = 0; e < 7; ++e) {
        for (int o = 32; o > 0; o >>= 1) {
            ar[e] += __shfl_xor(ar[e], o);
            an[e] += __shfl_xor(an[e], o);
        }
    }
    if (lane == 0) {
#pragma unroll
        for (int e = 0; e < 7; ++e) { arO[t * 7 + e] = ar[e]; anO[t * 7 + e] = an[e]; }
    }
}

// ---------------- router tail + count ----------------
__global__ void k_tail(const double* __restrict__ arO, const double* __restrict__ anO,
                       const float* __restrict__ noise,
                       const float* __restrict__ br, const float* __restrict__ bn,
                       int* __restrict__ idx0, int* __restrict__ idx1,
                       float* __restrict__ p0, float* __restrict__ p1,
                       int* __restrict__ cntA, double* __restrict__ sumA) {
    int t = blockIdx.x * 256 + threadIdx.x;
    int lane = threadIdx.x & 63;
    double best = -1e300, second = -1e300; int b0 = 0, b1 = 0;
#pragma unroll
    for (int e = 0; e < 7; ++e) {
        double lg = arO[t * 7 + e] + (double)br[e];
        double z  = anO[t * 7 + e] + (double)bn[e];
        double sp = (z > 30.0) ? (z + log1p(exp(-z))) : log1p(exp(z));
        double v  = lg + (double)noise[t * 7 + e] * sp;
        if (v > best)        { second = best; b1 = b0; best = v; b0 = e; }
        else if (v > second) { second = v; b1 = e; }
    }
    double ex = exp(second - best);
    float q0 = (float)(1.0 / (1.0 + ex));
    float q1 = (float)(ex / (1.0 + ex));
    idx0[t] = b0; idx1[t] = b1; p0[t] = q0; p1[t] = q1;
    int chunk = t >> 6;
    double dq0 = (double)q0, dq1 = (double)q1;
#pragma unroll
    for (int e = 0; e < 7; ++e) {
        unsigned long long m = __ballot((b0 == e) || (b1 == e));
        double q = (b0 == e ? dq0 : 0.0) + (b1 == e ? dq1 : 0.0);
        for (int o = 32; o > 0; o >>= 1) q += __shfl_xor(q, o);
        if (lane == 0) { cntA[e * 128 + chunk] = __popcll(m); sumA[e * 128 + chunk] = q; }
    }
}

// ---------------- phase B: exclusive scan of chunk counts + lbl -> out ----------------
__global__ void k_scanbase(const int* __restrict__ cntA, const double* __restrict__ sumA,
                           int* __restrict__ baseA, int* __restrict__ cnt,
                           float* __restrict__ out) {
    __shared__ int s[128];
    __shared__ double rd[128];
    __shared__ int rawc[7];
    __shared__ double ps[7];
    int tid = threadIdx.x;
    for (int e = 0; e < 7; ++e) {
        int v = 0;
        if (tid < 128) { v = cntA[e * 128 + tid]; s[tid] = v; }
        if (tid < 128) rd[tid] = sumA[e * 128 + tid];
        __syncthreads();
        for (int o = 1; o < 128; o <<= 1) {
            int add = 0;
            if (tid < 128 && tid >= o) add = s[tid - o];
            __syncthreads();
            if (tid < 128) s[tid] += add;
            __syncthreads();
        }
        if (tid < 128) baseA[e * 128 + tid] = s[tid] - v;
        if (tid == 127) { rawc[e] = s[127]; cnt[e] = (s[127] < CAPC) ? s[127] : CAPC; }
        for (int o = 64; o > 0; o >>= 1) {
            if (tid < o) rd[tid] += rd[tid + o];
            __syncthreads();
        }
        if (tid == 0) ps[e] = rd[0];
        __syncthreads();
    }
    if (tid == 0) {
        double acc = 0.0;
        for (int e = 0; e < 7; ++e) acc += ps[e] * (double)rawc[e];
        out[(long)NTOK * DDIM] = (float)(7.0 * acc / (8192.0 * 8192.0));
    }
}

// ---------------- phase C: slot assignment (FCFS, capacity-dropped) ----------------
__global__ void k_assign(const int* __restrict__ idx0, const int* __restrict__ idx1,
                         const int* __restrict__ baseA, int* __restrict__ slot_token,
                         int* __restrict__ ts0, int* __restrict__ ts1) {
    int lane = threadIdx.x & 63;
    int chunk = (blockIdx.x * 256 + threadIdx.x) >> 6;
    int t = chunk * 64 + lane;
    int i0 = idx0[t], i1 = idx1[t];
    int myts0 = -1, myts1 = -1;
    unsigned long long lt = (1ull << lane) - 1ull;
#pragma unroll
    for (int e = 0; e < 7; ++e) {
        bool has = (i0 == e) || (i1 == e);
        unsigned long long m = __ballot(has);
        int pre = __popcll(m & lt);
        int pos = baseA[e * 128 + chunk] + pre;
        if (has && pos < CAPC) {
            int slot = e * CPAD + pos;
            slot_token[slot] = t;
            if (i0 == e) myts0 = slot; else myts1 = slot;
        }
    }
    ts0[t] = myts0; ts1[t] = myts1;
}

// ---------------- 256x256 8-phase MFMA GEMM (T2 swizzle + T3/T4 counted prefetch + T5) ----------------
// 512 thr = 8 waves (2M x 4N), per-wave output 128x64, BK=64, 128 KiB dbuf dynamic LDS.
// Per K-tile: 4 phases {ds_read quadrant ; issue prefetch of T+1 ; bar ; setprio ; 16 MFMA ; setprio ; bar}.
// Only vmcnt(0) is at the K-tile boundary, >= 2 phases after the last staging issue.

#define READ_A(MQ)                                                                      \
    _Pragma("unroll")                                                                   \
    for (int j = 0; j < 4; ++j) {                                                       \
        int row_ = wm * 128 + (MQ) * 64 + j * 16 + rl;                                  \
        _Pragma("unroll")                                                               \
        for (int kh = 0; kh < 2; ++kh)                                                  \
            af[j][kh] = *(const bf16x8*)&sA[row_ * 64 + (((kh * 4 + quad) ^ kq7)) * 8]; \
    }

#define READ_B(NQ)                                                                      \
    _Pragma("unroll")                                                                   \
    for (int j = 0; j < 2; ++j) {                                                       \
        int row_ = wn * 64 + (NQ) * 32 + j * 16 + rl;                                   \
        _Pragma("unroll")                                                               \
        for (int kh = 0; kh < 2; ++kh)                                                  \
            bf[j][kh] = *(const bf16x8*)&sB[row_ * 64 + (((kh * 4 + quad) ^ kq7)) * 8]; \
    }

#define MFMA_Q(MQ, NQ)                                                                  \
    _Pragma("unroll")                                                                   \
    for (int kh = 0; kh < 2; ++kh)                                                      \
        _Pragma("unroll")                                                               \
        for (int j = 0; j < 4; ++j)                                                     \
            _Pragma("unroll")                                                           \
            for (int i = 0; i < 2; ++i)                                                 \
                acc[(MQ) * 4 + j][(NQ) * 2 + i] =                                       \
                    __builtin_amdgcn_mfma_f32_16x16x32_bf16(                            \
                        af[j][kh], bf[i][kh], acc[(MQ) * 4 + j][(NQ) * 2 + i], 0, 0, 0);

template <bool GATHER, bool MODE_H>
__global__ __launch_bounds__(512, 2) void k_gemm8(
    const u16* __restrict__ AbaseE, const u16* __restrict__ AbaseS,
    const int* __restrict__ gidx, const u16* __restrict__ zrow,
    const u16* __restrict__ WtE, const u16* __restrict__ WtS,
    const float* __restrict__ biasE, const float* __restrict__ biasS,
    u16* __restrict__ outE, u16* __restrict__ outS,
    const int* __restrict__ cnt) {
    extern __shared__ __align__(16) u16 lds[];   // 2 slots x (A 16384 + B 16384) u16 = 128 KiB
    int bid = blockIdx.x;
    int tid = threadIdx.x, lane = tid & 63, wv = tid >> 6;   // wv 0..7
    int lrow = lane >> 3, lkg = lane & 7, kgs = lkg ^ lrow;

    int e = 0, my, nx, mbound;
    const u16* Ab; const u16* Bb; const float* bias; u16* outp;
    bool gather = false;
    if (bid < EB8) {
        e = bid / 44; int r = bid % 44; my = r >> 2; nx = r & 3;
        if (my * 256 >= cnt[e]) return;
        Ab = GATHER ? AbaseE : (AbaseE + (long)e * CPAD * 1024);
        Bb = WtE + ((long)e << 20);
        bias = biasE + e * 1024;
        outp = outE + (long)e * CPAD * 1024;
        gather = GATHER;
        mbound = CPAD;
    } else {
        int sb = bid - EB8; my = sb >> 2; nx = sb & 3;
        Ab = AbaseS; Bb = WtS; bias = biasS; outp = outS;
        mbound = NTOK;
    }
    int m0 = my * 256, n0 = nx * 256;

    // per-lane staged-row pointers: wave wv stages A rows (wv*4+i)*8+lrow and B rows likewise
    const u16* arow[4];
    const u16* brow[4];
#pragma unroll
    for (int i = 0; i < 4; ++i) {
        int r = (wv * 4 + i) * 8 + lrow;     // 0..255
        if (gather) {
            int tok = gidx[e * CPAD + m0 + r];            // slot_token padded +128 entries
            arow[i] = (tok < NTOK) ? (AbaseE + (long)tok * DDIM) : zrow;
        } else {
            int rr = m0 + r; if (rr >= mbound) rr = 0;    // clamp partial last tile (rows unused)
            arow[i] = Ab + (long)rr * DDIM;
        }
        brow[i] = Bb + (long)(n0 + r) * DDIM;
    }

    f32x4 acc[8][4];
#pragma unroll
    for (int a = 0; a < 8; ++a)
#pragma unroll
        for (int b = 0; b < 4; ++b) { f32x4 z = {0.f, 0.f, 0.f, 0.f}; acc[a][b] = z; }

    int rl = lane & 15, quad = lane >> 4, kq7 = rl & 7;
    int wm = wv >> 2, wn = wv & 3;
    u16* s0 = lds;
    u16* s1 = lds + 32768;

    // prologue: stage K-tile 0 into slot 0 (linear dest, source col pre-swizzled by kgs)
#pragma unroll
    for (int i = 0; i < 4; ++i) {
        gl2lds16(arow[i] + kgs * 8, s0 + (wv * 4 + i) * 512);
        gl2lds16(brow[i] + kgs * 8, s0 + 16384 + (wv * 4 + i) * 512);
    }
    WAITV0();
    BAR();

    bf16x8 af[4][2], bf[2][2];
    for (int T = 0; T < 16; ++T) {
        u16* sc = (T & 1) ? s1 : s0;
        u16* sn = (T & 1) ? s0 : s1;
        const u16* sA = sc;
        const u16* sB = sc + 16384;
        int k1 = (T + 1) * 64;
        // ---- P1: read A(mq0)+B(nq0) ; issue A-prefetch of T+1
        READ_A(0)
        READ_B(0)
        if (T < 15) {
#pragma unroll
            for (int i = 0; i < 4; ++i)
                gl2lds16(arow[i] + k1 + kgs * 8, sn + (wv * 4 + i) * 512);
        }
        BAR();
        __builtin_amdgcn_s_setprio(1);
        MFMA_Q(0, 0)
        __builtin_amdgcn_s_setprio(0);
        BAR();
        // ---- P2: read B(nq1) ; issue B-prefetch of T+1
        READ_B(1)
        if (T < 15) {
#pragma unroll
            for (int i = 0; i < 4; ++i)
                gl2lds16(brow[i] + k1 + kgs * 8, sn + 16384 + (wv * 4 + i) * 512);
        }
        BAR();
        __builtin_amdgcn_s_setprio(1);
        MFMA_Q(0, 1)
        __builtin_amdgcn_s_setprio(0);
        BAR();
        // ---- P3: read A(mq1)
        READ_A(1)
        BAR();
        __builtin_amdgcn_s_setprio(1);
        MFMA_Q(1, 1)
        __builtin_amdgcn_s_setprio(0);
        BAR();
        // ---- P4: re-read B(nq0) ; K-tile boundary wait (issued >=2 phases ago -> hidden)
        READ_B(0)
        BAR();
        __builtin_amdgcn_s_setprio(1);
        MFMA_Q(1, 0)
        __builtin_amdgcn_s_setprio(0);
        WAITV0();
        BAR();
        __builtin_amdgcn_sched_barrier(0);
    }

    // epilogue: C/D layout col = lane&15, row = quad*4 + reg
#pragma unroll
    for (int ni = 0; ni < 4; ++ni) {
        int col = n0 + wn * 64 + ni * 16 + rl;
        float bv = bias[col];
#pragma unroll
        for (int mi = 0; mi < 8; ++mi) {
            int rowb = m0 + wm * 128 + mi * 16 + quad * 4;
#pragma unroll
            for (int r = 0; r < 4; ++r) {
                int rowg = rowb + r;
                if (rowg < mbound) {
                    float v = acc[mi][ni][r] + bv;
                    if constexpr (MODE_H) v = v > 0.f ? v : 0.f;
                    outp[(long)rowg * DDIM + col] = f2bf(v);
                }
            }
        }
    }
}

// ---------------- combine: out = Xs + g0*OutE[s0] + g1*OutE[s1] ----------------
__global__ __launch_bounds__(256) void k_combine(
    const u16* __restrict__ Xs, const u16* __restrict__ OutE,
    const int* __restrict__ ts0, const int* __restrict__ ts1,
    const float* __restrict__ p0, const float* __restrict__ p1,
    float* __restrict__ out) {
    int b = blockIdx.x;
    int d = threadIdx.x * 4;
    long base = (long)b * DDIM + d;
    ushort4 xs4 = *(const ushort4*)(Xs + base);
    float r0 = bf2f(xs4.x), r1 = bf2f(xs4.y), r2 = bf2f(xs4.z), r3 = bf2f(xs4.w);
    int s0 = ts0[b], s1 = ts1[b];
    if (s0 >= 0) {
        float g = p0[b];
        ushort4 o4 = *(const ushort4*)(OutE + (long)s0 * DDIM + d);
        r0 += g * bf2f(o4.x); r1 += g * bf2f(o4.y); r2 += g * bf2f(o4.z); r3 += g * bf2f(o4.w);
    }
    if (s1 >= 0) {
        float g = p1[b];
        ushort4 o4 = *(const ushort4*)(OutE + (long)s1 * DDIM + d);
        r0 += g * bf2f(o4.x); r1 += g * bf2f(o4.y); r2 += g * bf2f(o4.z); r3 += g * bf2f(o4.w);
    }
    float4 w; w.x = r0; w.y = r1; w.z = r2; w.w = r3;
    *(float4*)(out + base) = w;
}

extern "C" void kernel_launch(void* const* d_in, const int* in_sizes, int n_in,
                              void* d_out, int out_size, void* d_ws, size_t ws_size,
                              hipStream_t stream) {
    const float* x    = (const float*)d_in[0];
    const float* noise= (const float*)d_in[1];
    const float* Wr   = (const float*)d_in[2];
    const float* br   = (const float*)d_in[3];
    const float* Wn   = (const float*)d_in[4];
    const float* bn   = (const float*)d_in[5];
    const float* W1   = (const float*)d_in[6];
    const float* b1   = (const float*)d_in[7];
    const float* W2   = (const float*)d_in[8];
    const float* b2   = (const float*)d_in[9];
    const float* Ws1  = (const float*)d_in[10];
    const float* bs1  = (const float*)d_in[11];
    const float* Ws2  = (const float*)d_in[12];
    const float* bs2  = (const float*)d_in[13];
    float* out = (float*)d_out;
    char* ws = (char*)d_ws;

    size_t off = 0;
    auto alloc = [&](size_t bytes) { size_t o = off; off += (bytes + 255) & ~(size_t)255; return o; };
    u16*  Wt   = (u16*)(ws + alloc(7ull * 1048576 * 2));
    u16*  Wst  = (u16*)(ws + alloc(1048576ull * 2));
    u16*  xb   = (u16*)(ws + alloc((size_t)NTOK * 1024 * 2));
    u16*  He   = (u16*)(ws + alloc((size_t)NEXP * CPAD * 1024 * 2));
    u16*  Hs   = (u16*)(ws + alloc((size_t)NTOK * 1024 * 2));
    u16*  OutE = (u16*)(ws + alloc((size_t)NEXP * CPAD * 1024 * 2));
    u16*  Xs   = (u16*)(ws + alloc((size_t)NTOK * 1024 * 2));
    int*  idx0 = (int*)(ws + alloc(NTOK * 4));
    int*  idx1 = (int*)(ws + alloc(NTOK * 4));
    float* p0  = (float*)(ws + alloc(NTOK * 4));
    float* p1  = (float*)(ws + alloc(NTOK * 4));
    int*  ts0  = (int*)(ws + alloc(NTOK * 4));
    int*  ts1  = (int*)(ws + alloc(NTOK * 4));
    int*  slot_token = (int*)(ws + alloc((NEXP * CPAD + 128) * 4));
    int*  cntA = (int*)(ws + alloc(7 * 128 * 4));
    int*  baseA= (int*)(ws + alloc(7 * 128 * 4));
    double* sumA = (double*)(ws + alloc(7 * 128 * 8));
    int*  cnt    = (int*)(ws + alloc(8 * 4));
    u16*  zrow   = (u16*)(ws + alloc(1024 * 2));
    double* arO  = (double*)(ws + alloc((size_t)NTOK * 7 * 8));
    double* anO  = (double*)(ws + alloc((size_t)NTOK * 7 * 8));
    size_t base_off = off;
    // optional separate phase-2 transpose buffers (removes mid-pipeline bubble)
    u16*  Wt2  = (u16*)(ws + alloc(7ull * 1048576 * 2));
    u16*  Wst2 = (u16*)(ws + alloc(1048576ull * 2));

    if (base_off > ws_size) {
        k_zero<<<2048, 256, 0, stream>>>(out, (long)out_size);
        return;
    }
    bool sep = (off <= ws_size);
    if (!sep) { Wt2 = Wt; Wst2 = Wst; }

    // allow 128 KiB dynamic LDS on the GEMM kernels (host-side, capture-safe)
    (void)hipFuncSetAttribute((const void*)k_gemm8<true, true>,
                              hipFuncAttributeMaxDynamicSharedMemorySize, 131072);
    (void)hipFuncSetAttribute((const void*)k_gemm8<false, false>,
                              hipFuncAttributeMaxDynamicSharedMemorySize, 131072);

    // fused: x->bf16 + inits + transpose W1/Ws1 (+ W2/Ws2 when sep)
    k_prep<<<sep ? 12288 : 8192, 256, 0, stream>>>(
        x, xb, slot_token, zrow, W1, Ws1, Wt, Wst, W2, Ws2, Wt2, Wst2);
    k_router<<<1024, 512, 0, stream>>>(x, Wr, Wn, arO, anO);
    k_tail<<<32, 256, 0, stream>>>(arO, anO, noise, br, bn, idx0, idx1, p0, p1, cntA, sumA);
    k_scanbase<<<1, 256, 0, stream>>>(cntA, sumA, baseA, cnt, out);
    k_assign<<<32, 256, 0, stream>>>(idx0, idx1, baseA, slot_token, ts0, ts1);

    // fused layer 1: experts (gather xb via slot_token) + shared, relu -> bf16 He/Hs
    k_gemm8<true, true><<<TB8, 512, 131072, stream>>>(
        xb, xb, slot_token, zrow, Wt, Wst, b1, bs1, He, Hs, cnt);

    if (!sep)   // fallback: in-place phase-2 transpose between the GEMMs
        k_transpose<<<dim3(4, 128, 8), 256, 0, stream>>>(W2, Ws2, Wt, Wst);

    // fused layer 2: -> bf16 OutE/Xs (+b2/bs2)
    k_gemm8<false, false><<<TB8, 512, 131072, stream>>>(
        He, Hs, nullptr, zrow, Wt2, Wst2, b2, bs2, OutE, Xs, cnt);

    k_combine<<<NTOK, 256, 0, stream>>>(Xs, OutE, ts0, ts1, p0, p1, out);
    (void)in_sizes; (void)n_in; (void)out_size;
}

// Round 2
// 432.509 us; speedup vs baseline: 1.0062x; 1.0062x over previous
//
#include <hip/hip_runtime.h>
#include <math.h>

typedef unsigned short u16;
typedef __attribute__((ext_vector_type(4))) float f32x4;
typedef __bf16 bf16x8 __attribute__((ext_vector_type(8)));

#define NTOK 8192
#define DDIM 1024
#define NEXP 7
#define CAPC 2574      /* int(8192*2/7*1.1) */
#define CPAD 2688      /* 21*128 */
#define EB8 (NEXP * 11 * 4)     /* 308 expert blocks (256x256 tiles) */
#define TB8 (EB8 + 32 * 4)      /* + 128 shared blocks = 436 */
#define SWZQ (TB8 / 8)          /* 54 */
#define SWZR (TB8 % 8)          /* 4 */

__device__ inline float bf2f(u16 u) {
    union { unsigned int i; float f; } c; c.i = ((unsigned int)u) << 16; return c.f;
}
__device__ inline u16 f2bf(float f) {
    union { float f; unsigned int i; } c; c.f = f;
    unsigned int u = c.i;
    unsigned int r = (u + 0x7fffu + ((u >> 16) & 1u)) >> 16;
    return (u16)r;
}

__device__ inline void gl2lds16(const u16* g, const u16* l) {
    __builtin_amdgcn_global_load_lds(
        (const __attribute__((address_space(1))) unsigned int*)g,
        (__attribute__((address_space(3))) unsigned int*)l, 16, 0, 0);
}

#define BAR()    asm volatile("s_barrier" ::: "memory")
#define WAITV0() asm volatile("s_waitcnt vmcnt(0)" ::: "memory")
#define WAITV4() asm volatile("s_waitcnt vmcnt(4)" ::: "memory")
#define WAITV6() asm volatile("s_waitcnt vmcnt(6)" ::: "memory")

// ---------------- guard: zero the output (ws_size-too-small diagnostic) ----------------
__global__ void k_zero(float* out, long n) {
    long i = (long)blockIdx.x * 256 + threadIdx.x;
    long stride = (long)gridDim.x * 256;
    for (; i < n; i += stride) out[i] = 0.f;
}

// ---------------- fused prep ----------------
__global__ void k_prep(const float* __restrict__ x, u16* __restrict__ xb,
                       int* __restrict__ slot_token, u16* __restrict__ zrow,
                       const float* __restrict__ W1, const float* __restrict__ Ws1,
                       u16* __restrict__ Wt, u16* __restrict__ Wst,
                       const float* __restrict__ W2, const float* __restrict__ Ws2,
                       u16* __restrict__ Wt2, u16* __restrict__ Wst2) {
    int bid = blockIdx.x, tid = threadIdx.x;
    if (bid < 4096) {
        int gid = bid * 256 + tid;
        int i = gid * 8;
        float4 a = *(const float4*)(x + i);
        float4 b = *(const float4*)(x + i + 4);
        ushort4 o0; o0.x = f2bf(a.x); o0.y = f2bf(a.y); o0.z = f2bf(a.z); o0.w = f2bf(a.w);
        ushort4 o1; o1.x = f2bf(b.x); o1.y = f2bf(b.y); o1.z = f2bf(b.z); o1.w = f2bf(b.w);
        *(ushort4*)(xb + i) = o0;
        *(ushort4*)(xb + i + 4) = o1;
        if (gid < DDIM) zrow[gid] = 0;
        if (gid < NEXP * CPAD + 128) slot_token[gid] = NTOK;   /* +128 pad for 256-row tile over-read */
        return;
    }
    int phase2 = (bid >= 8192);
    int tb = bid - (phase2 ? 8192 : 4096);
    const float* srcE = phase2 ? W2 : W1;
    const float* srcS = phase2 ? Ws2 : Ws1;
    u16* dE = phase2 ? Wt2 : Wt;
    u16* dS = phase2 ? Wst2 : Wst;
    int z = tb >> 9; int rem = tb & 511;
    int y = rem >> 2; int xq = rem & 3;
    const float* src; u16* dst;
    if (z < 7) { src = srcE + (long)z * 1048576; dst = dE + (long)z * 1048576; }
    else       { src = srcS;                     dst = dS; }
    int n = xq * 256 + tid;
    int k0 = y * 8;
    u16 v[8];
#pragma unroll
    for (int j = 0; j < 8; ++j) v[j] = f2bf(src[(long)(k0 + j) * 1024 + n]);
    ushort4 a; a.x = v[0]; a.y = v[1]; a.z = v[2]; a.w = v[3];
    ushort4 b; b.x = v[4]; b.y = v[5]; b.z = v[6]; b.w = v[7];
    *(ushort4*)(dst + (long)n * 1024 + k0) = a;
    *(ushort4*)(dst + (long)n * 1024 + k0 + 4) = b;
}

// ---------------- weight transpose phase 2 (fallback when !sep) ----------------
__global__ void k_transpose(const float* __restrict__ srcE, const float* __restrict__ srcS,
                            u16* __restrict__ Wt, u16* __restrict__ Wst) {
    int z = blockIdx.z;
    const float* src; u16* dst;
    if (z < 7) { src = srcE + (long)z * 1048576; dst = Wt + (long)z * 1048576; }
    else       { src = srcS;                     dst = Wst; }
    int n = blockIdx.x * 256 + threadIdx.x;
    int k0 = blockIdx.y * 8;
    u16 v[8];
#pragma unroll
    for (int j = 0; j < 8; ++j) v[j] = f2bf(src[(long)(k0 + j) * 1024 + n]);
    ushort4 a; a.x = v[0]; a.y = v[1]; a.z = v[2]; a.w = v[3];
    ushort4 b; b.x = v[4]; b.y = v[5]; b.z = v[6]; b.w = v[7];
    *(ushort4*)(dst + (long)n * 1024 + k0) = a;
    *(ushort4*)(dst + (long)n * 1024 + k0 + 4) = b;
}

// ---------------- router main ----------------
__global__ __launch_bounds__(512) void k_router(
    const float* __restrict__ x,
    const float* __restrict__ Wr, const float* __restrict__ Wn,
    double* __restrict__ arO, double* __restrict__ anO) {
    __shared__ float swr[7168];
    __shared__ float swn[7168];
    int tid = threadIdx.x;
    for (int i = tid; i < 7168; i += 512) { swr[i] = Wr[i]; swn[i] = Wn[i]; }
    __syncthreads();
    int lane = tid & 63, wv = tid >> 6;
    int t = blockIdx.x * 8 + wv;
    double ar[7] = {0,0,0,0,0,0,0}, an[7] = {0,0,0,0,0,0,0};
    for (int j = 0; j < 16; ++j) {
        int d = j * 64 + lane;
        double xd = (double)x[t * 1024 + d];
#pragma unroll
        for (int e = 0; e < 7; ++e) {
            ar[e] += xd * (double)swr[d * 7 + e];
            an[e] += xd * (double)swn[d * 7 + e];
        }
    }
#pragma unroll
    for (int e = 0; e < 7; ++e) {
        for (int o = 32; o > 0; o >>= 1) {
            ar[e] += __shfl_xor(ar[e], o);
            an[e] += __shfl_xor(an[e], o);
        }
    }
    if (lane == 0) {
#pragma unroll
        for (int e = 0; e < 7; ++e) { arO[t * 7 + e] = ar[e]; anO[t * 7 + e] = an[e]; }
    }
}

// ---------------- router tail + count ----------------
__global__ void k_tail(const double* __restrict__ arO, const double* __restrict__ anO,
                       const float* __restrict__ noise,
                       const float* __restrict__ br, const float* __restrict__ bn,
                       int* __restrict__ idx0, int* __restrict__ idx1,
                       float* __restrict__ p0, float* __restrict__ p1,
                       int* __restrict__ cntA, double* __restrict__ sumA) {
    int t = blockIdx.x * 256 + threadIdx.x;
    int lane = threadIdx.x & 63;
    double best = -1e300, second = -1e300; int b0 = 0, b1 = 0;
#pragma unroll
    for (int e = 0; e < 7; ++e) {
        double lg = arO[t * 7 + e] + (double)br[e];
        double z  = anO[t * 7 + e] + (double)bn[e];
        double sp = (z > 30.0) ? (z + log1p(exp(-z))) : log1p(exp(z));
        double v  = lg + (double)noise[t * 7 + e] * sp;
        if (v > best)        { second = best; b1 = b0; best = v; b0 = e; }
        else if (v > second) { second = v; b1 = e; }
    }
    double ex = exp(second - best);
    float q0 = (float)(1.0 / (1.0 + ex));
    float q1 = (float)(ex / (1.0 + ex));
    idx0[t] = b0; idx1[t] = b1; p0[t] = q0; p1[t] = q1;
    int chunk = t >> 6;
    double dq0 = (double)q0, dq1 = (double)q1;
#pragma unroll
    for (int e = 0; e < 7; ++e) {
        unsigned long long m = __ballot((b0 == e) || (b1 == e));
        double q = (b0 == e ? dq0 : 0.0) + (b1 == e ? dq1 : 0.0);
        for (int o = 32; o > 0; o >>= 1) q += __shfl_xor(q, o);
        if (lane == 0) { cntA[e * 128 + chunk] = __popcll(m); sumA[e * 128 + chunk] = q; }
    }
}

// ---------------- phase B: exclusive scan + lbl ----------------
__global__ void k_scanbase(const int* __restrict__ cntA, const double* __restrict__ sumA,
                           int* __restrict__ baseA, int* __restrict__ cnt,
                           float* __restrict__ out) {
    __shared__ int s[128];
    __shared__ double rd[128];
    __shared__ int rawc[7];
    __shared__ double ps[7];
    int tid = threadIdx.x;
    for (int e = 0; e < 7; ++e) {
        int v = 0;
        if (tid < 128) { v = cntA[e * 128 + tid]; s[tid] = v; }
        if (tid < 128) rd[tid] = sumA[e * 128 + tid];
        __syncthreads();
        for (int o = 1; o < 128; o <<= 1) {
            int add = 0;
            if (tid < 128 && tid >= o) add = s[tid - o];
            __syncthreads();
            if (tid < 128) s[tid] += add;
            __syncthreads();
        }
        if (tid < 128) baseA[e * 128 + tid] = s[tid] - v;
        if (tid == 127) { rawc[e] = s[127]; cnt[e] = (s[127] < CAPC) ? s[127] : CAPC; }
        for (int o = 64; o > 0; o >>= 1) {
            if (tid < o) rd[tid] += rd[tid + o];
            __syncthreads();
        }
        if (tid == 0) ps[e] = rd[0];
        __syncthreads();
    }
    if (tid == 0) {
        double acc = 0.0;
        for (int e = 0; e < 7; ++e) acc += ps[e] * (double)rawc[e];
        out[(long)NTOK * DDIM] = (float)(7.0 * acc / (8192.0 * 8192.0));
    }
}

// ---------------- phase C: slot assignment ----------------
__global__ void k_assign(const int* __restrict__ idx0, const int* __restrict__ idx1,
                         const int* __restrict__ baseA, int* __restrict__ slot_token,
                         int* __restrict__ ts0, int* __restrict__ ts1) {
    int lane = threadIdx.x & 63;
    int chunk = (blockIdx.x * 256 + threadIdx.x) >> 6;
    int t = chunk * 64 + lane;
    int i0 = idx0[t], i1 = idx1[t];
    int myts0 = -1, myts1 = -1;
    unsigned long long lt = (1ull << lane) - 1ull;
#pragma unroll
    for (int e = 0; e < 7; ++e) {
        bool has = (i0 == e) || (i1 == e);
        unsigned long long m = __ballot(has);
        int pre = __popcll(m & lt);
        int pos = baseA[e * 128 + chunk] + pre;
        if (has && pos < CAPC) {
            int slot = e * CPAD + pos;
            slot_token[slot] = t;
            if (i0 == e) myts0 = slot; else myts1 = slot;
        }
    }
    ts0[t] = myts0; ts1[t] = myts1;
}

// ============ 256x256 8-phase GEMM, quadrant-aligned quarter staging, counted vmcnt ============
// 512 thr = 8 waves (2M x 4N); per-wave 128x64 out; BK=64; 128 KiB LDS (buf0=even tiles, buf1=odd).
// Quarter q(mq/nq) = rows read exactly in one phase -> frees 1 phase later -> staged there.
// Stage rotation: P1:Bq0(T+1) P2:Aq0(T+2) P3:Bq1(T+2) P4:Aq1(T+2)+vm4 P5:Bq0(T+2)
//                 P6:Aq0(T+3) P7:Bq1(T+3) P8:Aq1(T+3)+vm4.  Never drains below 4.

#define RD_AF(DST, MQ, BUF)                                                             \
    _Pragma("unroll")                                                                   \
    for (int j = 0; j < 4; ++j) {                                                       \
        int row_ = wm * 128 + (MQ) * 64 + j * 16 + rl;                                  \
        _Pragma("unroll")                                                               \
        for (int kh = 0; kh < 2; ++kh)                                                  \
            DST[j][kh] = *(const bf16x8*)&lds[(BUF) + row_ * 64 +                       \
                                              (((kh * 4 + quad) ^ kq7)) * 8];           \
    }

#define RD_BF(DST, NQ, BUF)                                                             \
    _Pragma("unroll")                                                                   \
    for (int j = 0; j < 2; ++j) {                                                       \
        int row_ = wn * 64 + (NQ) * 32 + j * 16 + rl;                                   \
        _Pragma("unroll")                                                               \
        for (int kh = 0; kh < 2; ++kh)                                                  \
            DST[j][kh] = *(const bf16x8*)&lds[(BUF) + 16384 + row_ * 64 +               \
                                              (((kh * 4 + quad) ^ kq7)) * 8];           \
    }

#define MM(MQ, NQ, AF, BF)                                                              \
    _Pragma("unroll")                                                                   \
    for (int kh = 0; kh < 2; ++kh)                                                      \
        _Pragma("unroll")                                                               \
        for (int j = 0; j < 4; ++j)                                                     \
            _Pragma("unroll")                                                           \
            for (int i = 0; i < 2; ++i)                                                 \
                acc[(MQ) * 4 + j][(NQ) * 2 + i] =                                       \
                    __builtin_amdgcn_mfma_f32_16x16x32_bf16(                            \
                        AF[j][kh], BF[i][kh], acc[(MQ) * 4 + j][(NQ) * 2 + i], 0, 0, 0);

#define STG_A(MQ, K, BUF) {                                                             \
    gl2lds16(pA[MQ][0] + (K) + kgs * 8, lds + (BUF) + dA[MQ][0]);                       \
    gl2lds16(pA[MQ][1] + (K) + kgs * 8, lds + (BUF) + dA[MQ][1]); }

#define STG_B(NQ, K, BUF) {                                                             \
    gl2lds16(pB[NQ][0] + (K) + kgs * 8, lds + (BUF) + dB[NQ][0]);                       \
    gl2lds16(pB[NQ][1] + (K) + kgs * 8, lds + (BUF) + dB[NQ][1]); }

#define PRIO1() __builtin_amdgcn_s_setprio(1)
#define PRIO0() __builtin_amdgcn_s_setprio(0)

template <bool GATHER, bool MODE_H>
__global__ __launch_bounds__(512, 2) void k_gemm8(
    const u16* __restrict__ AbaseE, const u16* __restrict__ AbaseS,
    const int* __restrict__ gidx, const u16* __restrict__ zrow,
    const u16* __restrict__ WtE, const u16* __restrict__ WtS,
    const float* __restrict__ biasE, const float* __restrict__ biasS,
    u16* __restrict__ outE, u16* __restrict__ outS,
    const int* __restrict__ cnt) {
    extern __shared__ __align__(16) u16 lds[];   // buf0 @0, buf1 @32768 (u16 units)
    // bijective XCD-chunked swizzle (T1): co-locate same-B-panel blocks on one XCD L2
    int phys = blockIdx.x;
    int xcd = phys & 7, seq = phys >> 3;
    int lid = (xcd < SWZR ? xcd * (SWZQ + 1) : SWZR * (SWZQ + 1) + (xcd - SWZR) * SWZQ) + seq;

    int tid = threadIdx.x, lane = tid & 63, wv = tid >> 6;   // wv 0..7
    int lrow = lane >> 3, lkg = lane & 7, kgs = lkg ^ lrow;

    int e = 0, my, nx, mbound;
    const u16* Ab; const u16* Bb; const float* bias; u16* outp;
    bool gather = false;
    if (lid < EB8) {
        e = lid / 44; int rr2 = lid % 44; nx = rr2 / 11; my = rr2 % 11;  // panel-grouped
        if (my * 256 >= cnt[e]) return;
        Ab = GATHER ? AbaseE : (AbaseE + (long)e * CPAD * 1024);
        Bb = WtE + ((long)e << 20);
        bias = biasE + e * 1024;
        outp = outE + (long)e * CPAD * 1024;
        gather = GATHER;
        mbound = CPAD;
    } else {
        int sb = lid - EB8; nx = sb >> 5; my = sb & 31;
        Ab = AbaseS; Bb = WtS; bias = biasS; outp = outS;
        mbound = NTOK;
    }
    int m0 = my * 256, n0 = nx * 256;

    // quarter staging pointers: A quarter (mq), group g = wv*2+j covers rows
    // (g>>3)*128 + mq*64 + (g&7)*8 + lrow; B quarter (nq): (g>>2)*64 + nq*32 + (g&3)*8 + lrow
    const u16* pA[2][2];
    const u16* pB[2][2];
    int dA[2][2], dB[2][2];
#pragma unroll
    for (int q = 0; q < 2; ++q)
#pragma unroll
        for (int j = 0; j < 2; ++j) {
            int g = wv * 2 + j;
            int ra = (g >> 3) * 128 + q * 64 + (g & 7) * 8;
            int rb = (g >> 2) * 64 + q * 32 + (g & 3) * 8;
            dA[q][j] = ra * 64;
            dB[q][j] = 16384 + rb * 64;
            if (gather) {
                int tok = gidx[e * CPAD + m0 + ra + lrow];
                pA[q][j] = (tok < NTOK) ? (AbaseE + (long)tok * DDIM) : zrow;
            } else {
                pA[q][j] = Ab + (long)(m0 + ra + lrow) * DDIM;
            }
            pB[q][j] = Bb + (long)(n0 + rb + lrow) * DDIM;
        }

    f32x4 acc[8][4];
#pragma unroll
    for (int a = 0; a < 8; ++a)
#pragma unroll
        for (int b = 0; b < 4; ++b) { f32x4 z = {0.f, 0.f, 0.f, 0.f}; acc[a][b] = z; }

    int rl = lane & 15, quad = lane >> 4, kq7 = rl & 7;
    int wm = wv >> 2, wn = wv & 3;

    // prologue: T0 all quarters -> buf0; T1 {Aq0,Bq1,Aq1} -> buf1 (Bq0(T1) arrives at P1)
    STG_A(0, 0, 0) STG_B(0, 0, 0) STG_B(1, 0, 0) STG_A(1, 0, 0)
    STG_A(0, 64, 32768) STG_B(1, 64, 32768) STG_A(1, 64, 32768)
    WAITV6();           // T0 complete; T1's 6 loads stay in flight
    BAR();

    bf16x8 afA[4][2], afB[4][2], bfA[2][2], bfB[2][2];
    for (int t = 0; t < 8; ++t) {
        int k1 = (2 * t + 1) * 64;
        int t2 = 2 * t + 2; int k2 = (t2 < 16 ? t2 : 0) * 64;   // clamped dummies keep vmcnt exact
        int t3 = 2 * t + 3; int k3 = (t3 < 16 ? t3 : 0) * 64;
        // ---- P1: Q(0,0) of tile 2t (buf0)
        RD_AF(afA, 0, 0) RD_BF(bfA, 0, 0)
        STG_B(0, k1, 32768)
        BAR(); PRIO1(); MM(0, 0, afA, bfA) PRIO0(); BAR();
        // ---- P2: Q(0,1)
        RD_BF(bfB, 1, 0)
        STG_A(0, k2, 0)
        BAR(); PRIO1(); MM(0, 1, afA, bfB) PRIO0(); BAR();
        // ---- P3: Q(1,1)
        RD_AF(afB, 1, 0)
        STG_B(1, k2, 0)
        BAR(); PRIO1(); MM(1, 1, afB, bfB) PRIO0(); BAR();
        // ---- P4: Q(1,0)
        RD_BF(bfA, 0, 0)
        STG_A(1, k2, 0)
        BAR(); PRIO1(); MM(1, 0, afB, bfA) PRIO0(); WAITV4(); BAR();
        // ---- P5: Q(0,0) of tile 2t+1 (buf1)
        RD_AF(afA, 0, 32768) RD_BF(bfA, 0, 32768)
        STG_B(0, k2, 0)
        BAR(); PRIO1(); MM(0, 0, afA, bfA) PRIO0(); BAR();
        // ---- P6: Q(0,1)
        RD_BF(bfB, 1, 32768)
        STG_A(0, k3, 32768)
        BAR(); PRIO1(); MM(0, 1, afA, bfB) PRIO0(); BAR();
        // ---- P7: Q(1,1)
        RD_AF(afB, 1, 32768)
        STG_B(1, k3, 32768)
        BAR(); PRIO1(); MM(1, 1, afB, bfB) PRIO0(); BAR();
        // ---- P8: Q(1,0)
        RD_BF(bfA, 0, 32768)
        STG_A(1, k3, 32768)
        BAR(); PRIO1(); MM(1, 0, afB, bfA) PRIO0(); WAITV4(); BAR();
    }
    WAITV0();   // drain tail dummy stages before exit

    // epilogue: C/D col = lane&15, row = quad*4 + reg; acc[mq*4+j][nq*2+i]
#pragma unroll
    for (int ni = 0; ni < 4; ++ni) {
        int col = n0 + wn * 64 + (ni >> 1) * 32 + (ni & 1) * 16 + rl;
        float bv = bias[col];
#pragma unroll
        for (int mi = 0; mi < 8; ++mi) {
            int rowb = m0 + wm * 128 + (mi >> 2) * 64 + (mi & 3) * 16 + quad * 4;
#pragma unroll
            for (int r = 0; r < 4; ++r) {
                int rowg = rowb + r;
                if (rowg < mbound) {
                    float v = acc[mi][ni][r] + bv;
                    if constexpr (MODE_H) v = v > 0.f ? v : 0.f;
                    outp[(long)rowg * DDIM + col] = f2bf(v);
                }
            }
        }
    }
}

// ---------------- combine ----------------
__global__ __launch_bounds__(256) void k_combine(
    const u16* __restrict__ Xs, const u16* __restrict__ OutE,
    const int* __restrict__ ts0, const int* __restrict__ ts1,
    const float* __restrict__ p0, const float* __restrict__ p1,
    float* __restrict__ out) {
    int b = blockIdx.x;
    int d = threadIdx.x * 4;
    long base = (long)b * DDIM + d;
    ushort4 xs4 = *(const ushort4*)(Xs + base);
    float r0 = bf2f(xs4.x), r1 = bf2f(xs4.y), r2 = bf2f(xs4.z), r3 = bf2f(xs4.w);
    int s0 = ts0[b], s1 = ts1[b];
    if (s0 >= 0) {
        float g = p0[b];
        ushort4 o4 = *(const ushort4*)(OutE + (long)s0 * DDIM + d);
        r0 += g * bf2f(o4.x); r1 += g * bf2f(o4.y); r2 += g * bf2f(o4.z); r3 += g * bf2f(o4.w);
    }
    if (s1 >= 0) {
        float g = p1[b];
        ushort4 o4 = *(const ushort4*)(OutE + (long)s1 * DDIM + d);
        r0 += g * bf2f(o4.x); r1 += g * bf2f(o4.y); r2 += g * bf2f(o4.z); r3 += g * bf2f(o4.w);
    }
    float4 w; w.x = r0; w.y = r1; w.z = r2; w.w = r3;
    *(float4*)(out + base) = w;
}

extern "C" void kernel_launch(void* const* d_in, const int* in_sizes, int n_in,
                              void* d_out, int out_size, void* d_ws, size_t ws_size,
                              hipStream_t stream) {
    const float* x    = (const float*)d_in[0];
    const float* noise= (const float*)d_in[1];
    const float* Wr   = (const float*)d_in[2];
    const float* br   = (const float*)d_in[3];
    const float* Wn   = (const float*)d_in[4];
    const float* bn   = (const float*)d_in[5];
    const float* W1   = (const float*)d_in[6];
    const float* b1   = (const float*)d_in[7];
    const float* W2   = (const float*)d_in[8];
    const float* b2   = (const float*)d_in[9];
    const float* Ws1  = (const float*)d_in[10];
    const float* bs1  = (const float*)d_in[11];
    const float* Ws2  = (const float*)d_in[12];
    const float* bs2  = (const float*)d_in[13];
    float* out = (float*)d_out;
    char* ws = (char*)d_ws;

    size_t off = 0;
    auto alloc = [&](size_t bytes) { size_t o = off; off += (bytes + 255) & ~(size_t)255; return o; };
    u16*  Wt   = (u16*)(ws + alloc(7ull * 1048576 * 2));
    u16*  Wst  = (u16*)(ws + alloc(1048576ull * 2));
    u16*  xb   = (u16*)(ws + alloc((size_t)NTOK * 1024 * 2));
    u16*  He   = (u16*)(ws + alloc((size_t)NEXP * CPAD * 1024 * 2));
    u16*  Hs   = (u16*)(ws + alloc((size_t)NTOK * 1024 * 2));
    u16*  OutE = (u16*)(ws + alloc((size_t)NEXP * CPAD * 1024 * 2));
    u16*  Xs   = (u16*)(ws + alloc((size_t)NTOK * 1024 * 2));
    int*  idx0 = (int*)(ws + alloc(NTOK * 4));
    int*  idx1 = (int*)(ws + alloc(NTOK * 4));
    float* p0  = (float*)(ws + alloc(NTOK * 4));
    float* p1  = (float*)(ws + alloc(NTOK * 4));
    int*  ts0  = (int*)(ws + alloc(NTOK * 4));
    int*  ts1  = (int*)(ws + alloc(NTOK * 4));
    int*  slot_token = (int*)(ws + alloc((NEXP * CPAD + 128) * 4));
    int*  cntA = (int*)(ws + alloc(7 * 128 * 4));
    int*  baseA= (int*)(ws + alloc(7 * 128 * 4));
    double* sumA = (double*)(ws + alloc(7 * 128 * 8));
    int*  cnt    = (int*)(ws + alloc(8 * 4));
    u16*  zrow   = (u16*)(ws + alloc(1024 * 2));
    double* arO  = (double*)(ws + alloc((size_t)NTOK * 7 * 8));
    double* anO  = (double*)(ws + alloc((size_t)NTOK * 7 * 8));
    size_t base_off = off;
    u16*  Wt2  = (u16*)(ws + alloc(7ull * 1048576 * 2));
    u16*  Wst2 = (u16*)(ws + alloc(1048576ull * 2));

    if (base_off > ws_size) {
        k_zero<<<2048, 256, 0, stream>>>(out, (long)out_size);
        return;
    }
    bool sep = (off <= ws_size);
    if (!sep) { Wt2 = Wt; Wst2 = Wst; }

    (void)hipFuncSetAttribute((const void*)k_gemm8<true, true>,
                              hipFuncAttributeMaxDynamicSharedMemorySize, 131072);
    (void)hipFuncSetAttribute((const void*)k_gemm8<false, false>,
                              hipFuncAttributeMaxDynamicSharedMemorySize, 131072);

    k_prep<<<sep ? 12288 : 8192, 256, 0, stream>>>(
        x, xb, slot_token, zrow, W1, Ws1, Wt, Wst, W2, Ws2, Wt2, Wst2);
    k_router<<<1024, 512, 0, stream>>>(x, Wr, Wn, arO, anO);
    k_tail<<<32, 256, 0, stream>>>(arO, anO, noise, br, bn, idx0, idx1, p0, p1, cntA, sumA);
    k_scanbase<<<1, 256, 0, stream>>>(cntA, sumA, baseA, cnt, out);
    k_assign<<<32, 256, 0, stream>>>(idx0, idx1, baseA, slot_token, ts0, ts1);

    k_gemm8<true, true><<<TB8, 512, 131072, stream>>>(
        xb, xb, slot_token, zrow, Wt, Wst, b1, bs1, He, Hs, cnt);

    if (!sep)
        k_transpose<<<dim3(4, 128, 8), 256, 0, stream>>>(W2, Ws2, Wt, Wst);

    k_gemm8<false, false><<<TB8, 512, 131072, stream>>>(
        He, Hs, nullptr, zrow, Wt2, Wst2, b2, bs2, OutE, Xs, cnt);

    k_combine<<<NTOK, 256, 0, stream>>>(Xs, OutE, ts0, ts1, p0, p1, out);
    (void)in_sizes; (void)n_in; (void)out_size;
}

// Round 3
// 427.644 us; speedup vs baseline: 1.0176x; 1.0114x over previous
//
#include <hip/hip_runtime.h>
#include <math.h>

typedef unsigned short u16;
typedef __attribute__((ext_vector_type(4))) float f32x4;
typedef __attribute__((ext_vector_type(4))) int v4i;
typedef __bf16 bf16x8 __attribute__((ext_vector_type(8)));

#define NTOK 8192
#define DDIM 1024
#define NEXP 7
#define CAPC 2574      /* int(8192*2/7*1.1) */
#define CPAD 2688      /* 21*128 */
#define EB8 (NEXP * 11 * 4)     /* 308 expert blocks (256x256 tiles) */
#define TB8 (EB8 + 32 * 4)      /* + 128 shared blocks = 436 */
#define SWZQ (TB8 / 8)          /* 54 */
#define SWZR (TB8 % 8)          /* 4 */

__device__ inline float bf2f(u16 u) {
    union { unsigned int i; float f; } c; c.i = ((unsigned int)u) << 16; return c.f;
}
__device__ inline u16 f2bf(float f) {
    union { float f; unsigned int i; } c; c.f = f;
    unsigned int u = c.i;
    unsigned int r = (u + 0x7fffu + ((u >> 16) & 1u)) >> 16;
    return (u16)r;
}

__device__ inline void gl2lds16(const u16* g, const u16* l) {
    __builtin_amdgcn_global_load_lds(
        (const __attribute__((address_space(1))) unsigned int*)g,
        (__attribute__((address_space(3))) unsigned int*)l, 16, 0, 0);
}

// NO memory clobbers anywhere below: a "memory" clobber (or compiler-visible
// aliasing LDS read) makes SIInsertWaitcnts emit vmcnt(0) drains that destroy
// the counted-prefetch pipeline (rounds 1-2 post-mortem).
#define BARRIER() __builtin_amdgcn_s_barrier()
#define SCHED0()  __builtin_amdgcn_sched_barrier(0)
#define PRIO1()   __builtin_amdgcn_s_setprio(1)
#define PRIO0()   __builtin_amdgcn_s_setprio(0)
#define LGKM0()   asm volatile("s_waitcnt lgkmcnt(0)")
#define WAITV6()  asm volatile("s_waitcnt vmcnt(6)")
#define WAITV0()  asm volatile("s_waitcnt vmcnt(0)")

// ---------------- guard: zero the output (ws_size-too-small diagnostic) ----------------
__global__ void k_zero(float* out, long n) {
    long i = (long)blockIdx.x * 256 + threadIdx.x;
    long stride = (long)gridDim.x * 256;
    for (; i < n; i += stride) out[i] = 0.f;
}

// ---------------- fused prep ----------------
__global__ void k_prep(const float* __restrict__ x, u16* __restrict__ xb,
                       int* __restrict__ slot_token, u16* __restrict__ zrow,
                       const float* __restrict__ W1, const float* __restrict__ Ws1,
                       u16* __restrict__ Wt, u16* __restrict__ Wst,
                       const float* __restrict__ W2, const float* __restrict__ Ws2,
                       u16* __restrict__ Wt2, u16* __restrict__ Wst2) {
    int bid = blockIdx.x, tid = threadIdx.x;
    if (bid < 4096) {
        int gid = bid * 256 + tid;
        int i = gid * 8;
        float4 a = *(const float4*)(x + i);
        float4 b = *(const float4*)(x + i + 4);
        ushort4 o0; o0.x = f2bf(a.x); o0.y = f2bf(a.y); o0.z = f2bf(a.z); o0.w = f2bf(a.w);
        ushort4 o1; o1.x = f2bf(b.x); o1.y = f2bf(b.y); o1.z = f2bf(b.z); o1.w = f2bf(b.w);
        *(ushort4*)(xb + i) = o0;
        *(ushort4*)(xb + i + 4) = o1;
        if (gid < DDIM) zrow[gid] = 0;
        if (gid < NEXP * CPAD + 128) slot_token[gid] = NTOK;   /* +128 pad for 256-row tile over-read */
        return;
    }
    int phase2 = (bid >= 8192);
    int tb = bid - (phase2 ? 8192 : 4096);
    const float* srcE = phase2 ? W2 : W1;
    const float* srcS = phase2 ? Ws2 : Ws1;
    u16* dE = phase2 ? Wt2 : Wt;
    u16* dS = phase2 ? Wst2 : Wst;
    int z = tb >> 9; int rem = tb & 511;
    int y = rem >> 2; int xq = rem & 3;
    const float* src; u16* dst;
    if (z < 7) { src = srcE + (long)z * 1048576; dst = dE + (long)z * 1048576; }
    else       { src = srcS;                     dst = dS; }
    int n = xq * 256 + tid;
    int k0 = y * 8;
    u16 v[8];
#pragma unroll
    for (int j = 0; j < 8; ++j) v[j] = f2bf(src[(long)(k0 + j) * 1024 + n]);
    ushort4 a; a.x = v[0]; a.y = v[1]; a.z = v[2]; a.w = v[3];
    ushort4 b; b.x = v[4]; b.y = v[5]; b.z = v[6]; b.w = v[7];
    *(ushort4*)(dst + (long)n * 1024 + k0) = a;
    *(ushort4*)(dst + (long)n * 1024 + k0 + 4) = b;
}

// ---------------- weight transpose phase 2 (fallback when !sep) ----------------
__global__ void k_transpose(const float* __restrict__ srcE, const float* __restrict__ srcS,
                            u16* __restrict__ Wt, u16* __restrict__ Wst) {
    int z = blockIdx.z;
    const float* src; u16* dst;
    if (z < 7) { src = srcE + (long)z * 1048576; dst = Wt + (long)z * 1048576; }
    else       { src = srcS;                     dst = Wst; }
    int n = blockIdx.x * 256 + threadIdx.x;
    int k0 = blockIdx.y * 8;
    u16 v[8];
#pragma unroll
    for (int j = 0; j < 8; ++j) v[j] = f2bf(src[(long)(k0 + j) * 1024 + n]);
    ushort4 a; a.x = v[0]; a.y = v[1]; a.z = v[2]; a.w = v[3];
    ushort4 b; b.x = v[4]; b.y = v[5]; b.z = v[6]; b.w = v[7];
    *(ushort4*)(dst + (long)n * 1024 + k0) = a;
    *(ushort4*)(dst + (long)n * 1024 + k0 + 4) = b;
}

// ---------------- router main ----------------
__global__ __launch_bounds__(512) void k_router(
    const float* __restrict__ x,
    const float* __restrict__ Wr, const float* __restrict__ Wn,
    double* __restrict__ arO, double* __restrict__ anO) {
    __shared__ float swr[7168];
    __shared__ float swn[7168];
    int tid = threadIdx.x;
    for (int i = tid; i < 7168; i += 512) { swr[i] = Wr[i]; swn[i] = Wn[i]; }
    __syncthreads();
    int lane = tid & 63, wv = tid >> 6;
    int t = blockIdx.x * 8 + wv;
    double ar[7] = {0,0,0,0,0,0,0}, an[7] = {0,0,0,0,0,0,0};
    for (int j = 0; j < 16; ++j) {
        int d = j * 64 + lane;
        double xd = (double)x[t * 1024 + d];
#pragma unroll
        for (int e = 0; e < 7; ++e) {
            ar[e] += xd * (double)swr[d * 7 + e];
            an[e] += xd * (double)swn[d * 7 + e];
        }
    }
#pragma unroll
    for (int e = 0; e < 7; ++e) {
        for (int o = 32; o > 0; o >>= 1) {
            ar[e] += __shfl_xor(ar[e], o);
            an[e] += __shfl_xor(an[e], o);
        }
    }
    if (lane == 0) {
#pragma unroll
        for (int e = 0; e < 7; ++e) { arO[t * 7 + e] = ar[e]; anO[t * 7 + e] = an[e]; }
    }
}

// ---------------- router tail + count ----------------
__global__ void k_tail(const double* __restrict__ arO, const double* __restrict__ anO,
                       const float* __restrict__ noise,
                       const float* __restrict__ br, const float* __restrict__ bn,
                       int* __restrict__ idx0, int* __restrict__ idx1,
                       float* __restrict__ p0, float* __restrict__ p1,
                       int* __restrict__ cntA, double* __restrict__ sumA) {
    int t = blockIdx.x * 256 + threadIdx.x;
    int lane = threadIdx.x & 63;
    double best = -1e300, second = -1e300; int b0 = 0, b1 = 0;
#pragma unroll
    for (int e = 0; e < 7; ++e) {
        double lg = arO[t * 7 + e] + (double)br[e];
        double z  = anO[t * 7 + e] + (double)bn[e];
        double sp = (z > 30.0) ? (z + log1p(exp(-z))) : log1p(exp(z));
        double v  = lg + (double)noise[t * 7 + e] * sp;
        if (v > best)        { second = best; b1 = b0; best = v; b0 = e; }
        else if (v > second) { second = v; b1 = e; }
    }
    double ex = exp(second - best);
    float q0 = (float)(1.0 / (1.0 + ex));
    float q1 = (float)(ex / (1.0 + ex));
    idx0[t] = b0; idx1[t] = b1; p0[t] = q0; p1[t] = q1;
    int chunk = t >> 6;
    double dq0 = (double)q0, dq1 = (double)q1;
#pragma unroll
    for (int e = 0; e < 7; ++e) {
        unsigned long long m = __ballot((b0 == e) || (b1 == e));
        double q = (b0 == e ? dq0 : 0.0) + (b1 == e ? dq1 : 0.0);
        for (int o = 32; o > 0; o >>= 1) q += __shfl_xor(q, o);
        if (lane == 0) { cntA[e * 128 + chunk] = __popcll(m); sumA[e * 128 + chunk] = q; }
    }
}

// ---------------- phase B: exclusive scan + lbl ----------------
__global__ void k_scanbase(const int* __restrict__ cntA, const double* __restrict__ sumA,
                           int* __restrict__ baseA, int* __restrict__ cnt,
                           float* __restrict__ out) {
    __shared__ int s[128];
    __shared__ double rd[128];
    __shared__ int rawc[7];
    __shared__ double ps[7];
    int tid = threadIdx.x;
    for (int e = 0; e < 7; ++e) {
        int v = 0;
        if (tid < 128) { v = cntA[e * 128 + tid]; s[tid] = v; }
        if (tid < 128) rd[tid] = sumA[e * 128 + tid];
        __syncthreads();
        for (int o = 1; o < 128; o <<= 1) {
            int add = 0;
            if (tid < 128 && tid >= o) add = s[tid - o];
            __syncthreads();
            if (tid < 128) s[tid] += add;
            __syncthreads();
        }
        if (tid < 128) baseA[e * 128 + tid] = s[tid] - v;
        if (tid == 127) { rawc[e] = s[127]; cnt[e] = (s[127] < CAPC) ? s[127] : CAPC; }
        for (int o = 64; o > 0; o >>= 1) {
            if (tid < o) rd[tid] += rd[tid + o];
            __syncthreads();
        }
        if (tid == 0) ps[e] = rd[0];
        __syncthreads();
    }
    if (tid == 0) {
        double acc = 0.0;
        for (int e = 0; e < 7; ++e) acc += ps[e] * (double)rawc[e];
        out[(long)NTOK * DDIM] = (float)(7.0 * acc / (8192.0 * 8192.0));
    }
}

// ---------------- phase C: slot assignment ----------------
__global__ void k_assign(const int* __restrict__ idx0, const int* __restrict__ idx1,
                         const int* __restrict__ baseA, int* __restrict__ slot_token,
                         int* __restrict__ ts0, int* __restrict__ ts1) {
    int lane = threadIdx.x & 63;
    int chunk = (blockIdx.x * 256 + threadIdx.x) >> 6;
    int t = chunk * 64 + lane;
    int i0 = idx0[t], i1 = idx1[t];
    int myts0 = -1, myts1 = -1;
    unsigned long long lt = (1ull << lane) - 1ull;
#pragma unroll
    for (int e = 0; e < 7; ++e) {
        bool has = (i0 == e) || (i1 == e);
        unsigned long long m = __ballot(has);
        int pre = __popcll(m & lt);
        int pos = baseA[e * 128 + chunk] + pre;
        if (has && pos < CAPC) {
            int slot = e * CPAD + pos;
            slot_token[slot] = t;
            if (i0 == e) myts0 = slot; else myts1 = slot;
        }
    }
    ts0[t] = myts0; ts1[t] = myts1;
}

// ============ 256x256 8-phase GEMM — asm ds_read, builtin barriers, counted vmcnt(6) ============
// 512 thr = 8 waves (2M x 4N); per-wave 128x64 out; BK=64; 128 KiB LDS (buf0=even, buf1=odd tiles).
// Stage rotation (groups of 2 loads): P1:Bq0(T+1) P2:Aq0(T+2) P3:Bq1(T+2) P4:Aq1(T+2)+vm6
//                                     P5:Bq0(T+2) P6:Aq0(T+3) P7:Bq1(T+3) P8:Aq1(T+3)+vm6.
// Oldest load waited on is always >= 3 phases in flight. All LDS reads are inline asm so the
// compiler cannot insert aliasing-based vmcnt drains; barriers are the builtin (no drain).

union Fr { v4i i; bf16x8 h; };

#define DSR(DST, ADDR, OFF) \
    asm volatile("ds_read_b128 %0, %1 offset:%c2" : "=v"(DST) : "v"(ADDR), "i"(OFF));

#define RD_A(F, MQ, A0, A1)                               \
    _Pragma("unroll")                                     \
    for (int j = 0; j < 4; ++j) {                         \
        DSR(F[j][0].i, A0, (MQ) * 8192 + j * 2048)        \
        DSR(F[j][1].i, A1, (MQ) * 8192 + j * 2048)        \
    }

#define RD_B(F, NQ, B0, B1)                               \
    _Pragma("unroll")                                     \
    for (int j = 0; j < 2; ++j) {                         \
        DSR(F[j][0].i, B0, (NQ) * 4096 + j * 2048)        \
        DSR(F[j][1].i, B1, (NQ) * 4096 + j * 2048)        \
    }

#define MM(MQ, NQ, AF, BF)                                                              \
    _Pragma("unroll")                                                                   \
    for (int kh = 0; kh < 2; ++kh)                                                      \
        _Pragma("unroll")                                                               \
        for (int j = 0; j < 4; ++j)                                                     \
            _Pragma("unroll")                                                           \
            for (int i = 0; i < 2; ++i)                                                 \
                acc[(MQ) * 4 + j][(NQ) * 2 + i] =                                       \
                    __builtin_amdgcn_mfma_f32_16x16x32_bf16(                            \
                        AF[j][kh].h, BF[i][kh].h, acc[(MQ) * 4 + j][(NQ) * 2 + i], 0, 0, 0);

#define STG_A(MQ, K, BUFB) {                                                            \
    gl2lds16(pA[MQ][0] + (K) + kgs * 8, lds + (BUFB) + dA0 + (MQ) * 4096);              \
    gl2lds16(pA[MQ][1] + (K) + kgs * 8, lds + (BUFB) + dA1 + (MQ) * 4096); }

#define STG_B(NQ, K, BUFB) {                                                            \
    gl2lds16(pBb + (NQ) * 32768 + (K) + kgs * 8, lds + (BUFB) + dB0 + (NQ) * 2048);     \
    gl2lds16(pBb + (NQ) * 32768 + 8192 + (K) + kgs * 8,                                 \
             lds + (BUFB) + dB0 + (NQ) * 2048 + 512); }

template <bool GATHER, bool MODE_H>
__global__ __launch_bounds__(512, 2) void k_gemm8(
    const u16* __restrict__ AbaseE, const u16* __restrict__ AbaseS,
    const int* __restrict__ gidx, const u16* __restrict__ zrow,
    const u16* __restrict__ WtE, const u16* __restrict__ WtS,
    const float* __restrict__ biasE, const float* __restrict__ biasS,
    u16* __restrict__ outE, u16* __restrict__ outS,
    const int* __restrict__ cnt) {
    extern __shared__ __align__(16) u16 lds[];   // buf0 @0, buf1 @32768 (u16 units)
    // bijective XCD-chunked swizzle (T1)
    int phys = blockIdx.x;
    int xcd = phys & 7, seq = phys >> 3;
    int lid = (xcd < SWZR ? xcd * (SWZQ + 1) : SWZR * (SWZQ + 1) + (xcd - SWZR) * SWZQ) + seq;

    int tid = threadIdx.x, lane = tid & 63, wv = tid >> 6;   // wv 0..7
    int lrow = lane >> 3, lkg = lane & 7, kgs = lkg ^ lrow;

    int e = 0, my, nx, mbound;
    const u16* Ab; const u16* Bb; const float* bias; u16* outp;
    bool gather = false;
    if (lid < EB8) {
        e = lid / 44; int r2 = lid % 44; nx = r2 / 11; my = r2 % 11;  // panel-grouped
        if (my * 256 >= cnt[e]) return;
        Ab = GATHER ? AbaseE : (AbaseE + (long)e * CPAD * 1024);
        Bb = WtE + ((long)e << 20);
        bias = biasE + e * 1024;
        outp = outE + (long)e * CPAD * 1024;
        gather = GATHER;
        mbound = CPAD;
    } else {
        int sb = lid - EB8; nx = sb >> 5; my = sb & 31;
        Ab = AbaseS; Bb = WtS; bias = biasS; outp = outS;
        mbound = NTOK;
    }
    int m0 = my * 256, n0 = nx * 256;

    // ---- staging pointers ----
    // A quarter (mq), group g = wv*2+j: rows (g>>3)*128 + mq*64 + (g&7)*8 + lrow (gathered)
    const u16* pA[2][2];
    int g0 = wv * 2, g1 = wv * 2 + 1;
#pragma unroll
    for (int q = 0; q < 2; ++q)
#pragma unroll
        for (int j = 0; j < 2; ++j) {
            int g = wv * 2 + j;
            int ra = (g >> 3) * 128 + q * 64 + (g & 7) * 8;
            if (gather) {
                int tok = gidx[e * CPAD + m0 + ra + lrow];
                pA[q][j] = (tok < NTOK) ? (AbaseE + (long)tok * DDIM) : zrow;
            } else {
                pA[q][j] = Ab + (long)(m0 + ra + lrow) * DDIM;
            }
        }
    // B base: row (g0>>2)*64 + (g0&3)*8 + lrow; (q,j) offsets are q*32768 + j*8192 u16
    const u16* pBb = Bb + (long)(n0 + (g0 >> 2) * 64 + (g0 & 3) * 8 + lrow) * DDIM;
    // LDS dest offsets (u16 units, wave-uniform)
    int dA0 = (g0 >> 3) * 8192 + (g0 & 7) * 512;
    int dA1 = (g1 >> 3) * 8192 + (g1 & 7) * 512;
    int dB0 = 16384 + (g0 >> 2) * 4096 + (g0 & 3) * 512;

    f32x4 acc[8][4];
#pragma unroll
    for (int a = 0; a < 8; ++a)
#pragma unroll
        for (int b = 0; b < 4; ++b) { f32x4 z = {0.f, 0.f, 0.f, 0.f}; acc[a][b] = z; }

    int rl = lane & 15, quad = lane >> 4, kq7 = rl & 7;
    int wm = wv >> 2, wn = wv & 3;

    // ---- ds_read byte addresses (LDS offset of dynamic base + tile offsets) ----
    unsigned L0 = (unsigned)(uintptr_t)(__attribute__((address_space(3))) u16*)lds;
    int swz0 = ((quad ^ kq7) & 7) * 16;
    int aA00 = (int)L0 + (wm * 128 + rl) * 128 + swz0;   // buf0, kh=0
    int aA01 = aA00 ^ 64;                                // buf0, kh=1 (toggle bit2 of swz)
    int aA10 = aA00 + 65536, aA11 = aA01 + 65536;        // buf1
    int bB00 = (int)L0 + 32768 + (wn * 64 + rl) * 128 + swz0;
    int bB01 = bB00 ^ 64;
    int bB10 = bB00 + 65536, bB11 = bB01 + 65536;

    // ---- prologue: T0 {Aq0,Bq0,Bq1,Aq1}->buf0, T1 {Aq0,Bq1,Aq1}->buf1 (Bq0(T1) at P1) ----
    STG_A(0, 0, 0) STG_B(0, 0, 0) STG_B(1, 0, 0) STG_A(1, 0, 0)
    STG_A(0, 64, 32768) STG_B(1, 64, 32768) STG_A(1, 64, 32768)
    WAITV6();           // T0 complete; T1's 6 loads remain in flight
    BARRIER(); SCHED0();

    Fr afA[4][2], afB[4][2], bfA[2][2], bfB[2][2];
    for (int t = 0; t < 8; ++t) {
        int k1 = (2 * t + 1) * 64;
        int t2 = 2 * t + 2; int k2 = (t2 < 16 ? t2 : 0) * 64;   // dummy re-stage keeps vmcnt exact
        int t3 = 2 * t + 3; int k3 = (t3 < 16 ? t3 : 0) * 64;
        // ===== even tile 2t (buf0) =====
        // P1
        RD_A(afA, 0, aA00, aA01) RD_B(bfA, 0, bB00, bB01)
        STG_B(0, k1, 32768)
        BARRIER(); LGKM0(); SCHED0();
        PRIO1(); MM(0, 0, afA, bfA) PRIO0(); BARRIER(); SCHED0();
        // P2
        RD_B(bfB, 1, bB00, bB01)
        STG_A(0, k2, 0)
        BARRIER(); LGKM0(); SCHED0();
        PRIO1(); MM(0, 1, afA, bfB) PRIO0(); BARRIER(); SCHED0();
        // P3
        RD_A(afB, 1, aA00, aA01)
        STG_B(1, k2, 0)
        BARRIER(); LGKM0(); SCHED0();
        PRIO1(); MM(1, 1, afB, bfB) PRIO0(); BARRIER(); SCHED0();
        // P4
        RD_B(bfA, 0, bB00, bB01)
        STG_A(1, k2, 0)
        BARRIER(); LGKM0(); SCHED0();
        PRIO1(); MM(1, 0, afB, bfA) PRIO0(); WAITV6(); BARRIER(); SCHED0();
        // ===== odd tile 2t+1 (buf1) =====
        // P5
        RD_A(afA, 0, aA10, aA11) RD_B(bfA, 0, bB10, bB11)
        STG_B(0, k2, 0)
        BARRIER(); LGKM0(); SCHED0();
        PRIO1(); MM(0, 0, afA, bfA) PRIO0(); BARRIER(); SCHED0();
        // P6
        RD_B(bfB, 1, bB10, bB11)
        STG_A(0, k3, 32768)
        BARRIER(); LGKM0(); SCHED0();
        PRIO1(); MM(0, 1, afA, bfB) PRIO0(); BARRIER(); SCHED0();
        // P7
        RD_A(afB, 1, aA10, aA11)
        STG_B(1, k3, 32768)
        BARRIER(); LGKM0(); SCHED0();
        PRIO1(); MM(1, 1, afB, bfB) PRIO0(); BARRIER(); SCHED0();
        // P8
        RD_B(bfA, 0, bB10, bB11)
        STG_A(1, k3, 32768)
        BARRIER(); LGKM0(); SCHED0();
        PRIO1(); MM(1, 0, afB, bfA) PRIO0(); WAITV6(); BARRIER(); SCHED0();
    }
    WAITV0();   // drain tail dummy stages before exit

    // epilogue: C/D col = lane&15, row = quad*4 + reg; acc[mq*4+j][nq*2+i]
#pragma unroll
    for (int ni = 0; ni < 4; ++ni) {
        int col = n0 + wn * 64 + (ni >> 1) * 32 + (ni & 1) * 16 + rl;
        float bv = bias[col];
#pragma unroll
        for (int mi = 0; mi < 8; ++mi) {
            int rowb = m0 + wm * 128 + (mi >> 2) * 64 + (mi & 3) * 16 + quad * 4;
#pragma unroll
            for (int r = 0; r < 4; ++r) {
                int rowg = rowb + r;
                if (rowg < mbound) {
                    float v = acc[mi][ni][r] + bv;
                    if constexpr (MODE_H) v = v > 0.f ? v : 0.f;
                    outp[(long)rowg * DDIM + col] = f2bf(v);
                }
            }
        }
    }
}

// ---------------- combine ----------------
__global__ __launch_bounds__(256) void k_combine(
    const u16* __restrict__ Xs, const u16* __restrict__ OutE,
    const int* __restrict__ ts0, const int* __restrict__ ts1,
    const float* __restrict__ p0, const float* __restrict__ p1,
    float* __restrict__ out) {
    int b = blockIdx.x;
    int d = threadIdx.x * 4;
    long base = (long)b * DDIM + d;
    ushort4 xs4 = *(const ushort4*)(Xs + base);
    float r0 = bf2f(xs4.x), r1 = bf2f(xs4.y), r2 = bf2f(xs4.z), r3 = bf2f(xs4.w);
    int s0 = ts0[b], s1 = ts1[b];
    if (s0 >= 0) {
        float g = p0[b];
        ushort4 o4 = *(const ushort4*)(OutE + (long)s0 * DDIM + d);
        r0 += g * bf2f(o4.x); r1 += g * bf2f(o4.y); r2 += g * bf2f(o4.z); r3 += g * bf2f(o4.w);
    }
    if (s1 >= 0) {
        float g = p1[b];
        ushort4 o4 = *(const ushort4*)(OutE + (long)s1 * DDIM + d);
        r0 += g * bf2f(o4.x); r1 += g * bf2f(o4.y); r2 += g * bf2f(o4.z); r3 += g * bf2f(o4.w);
    }
    float4 w; w.x = r0; w.y = r1; w.z = r2; w.w = r3;
    *(float4*)(out + base) = w;
}

extern "C" void kernel_launch(void* const* d_in, const int* in_sizes, int n_in,
                              void* d_out, int out_size, void* d_ws, size_t ws_size,
                              hipStream_t stream) {
    const float* x    = (const float*)d_in[0];
    const float* noise= (const float*)d_in[1];
    const float* Wr   = (const float*)d_in[2];
    const float* br   = (const float*)d_in[3];
    const float* Wn   = (const float*)d_in[4];
    const float* bn   = (const float*)d_in[5];
    const float* W1   = (const float*)d_in[6];
    const float* b1   = (const float*)d_in[7];
    const float* W2   = (const float*)d_in[8];
    const float* b2   = (const float*)d_in[9];
    const float* Ws1  = (const float*)d_in[10];
    const float* bs1  = (const float*)d_in[11];
    const float* Ws2  = (const float*)d_in[12];
    const float* bs2  = (const float*)d_in[13];
    float* out = (float*)d_out;
    char* ws = (char*)d_ws;

    size_t off = 0;
    auto alloc = [&](size_t bytes) { size_t o = off; off += (bytes + 255) & ~(size_t)255; return o; };
    u16*  Wt   = (u16*)(ws + alloc(7ull * 1048576 * 2));
    u16*  Wst  = (u16*)(ws + alloc(1048576ull * 2));
    u16*  xb   = (u16*)(ws + alloc((size_t)NTOK * 1024 * 2));
    u16*  He   = (u16*)(ws + alloc((size_t)NEXP * CPAD * 1024 * 2));
    u16*  Hs   = (u16*)(ws + alloc((size_t)NTOK * 1024 * 2));
    u16*  OutE = (u16*)(ws + alloc((size_t)NEXP * CPAD * 1024 * 2));
    u16*  Xs   = (u16*)(ws + alloc((size_t)NTOK * 1024 * 2));
    int*  idx0 = (int*)(ws + alloc(NTOK * 4));
    int*  idx1 = (int*)(ws + alloc(NTOK * 4));
    float* p0  = (float*)(ws + alloc(NTOK * 4));
    float* p1  = (float*)(ws + alloc(NTOK * 4));
    int*  ts0  = (int*)(ws + alloc(NTOK * 4));
    int*  ts1  = (int*)(ws + alloc(NTOK * 4));
    int*  slot_token = (int*)(ws + alloc((NEXP * CPAD + 128) * 4));
    int*  cntA = (int*)(ws + alloc(7 * 128 * 4));
    int*  baseA= (int*)(ws + alloc(7 * 128 * 4));
    double* sumA = (double*)(ws + alloc(7 * 128 * 8));
    int*  cnt    = (int*)(ws + alloc(8 * 4));
    u16*  zrow   = (u16*)(ws + alloc(1024 * 2));
    double* arO  = (double*)(ws + alloc((size_t)NTOK * 7 * 8));
    double* anO  = (double*)(ws + alloc((size_t)NTOK * 7 * 8));
    size_t base_off = off;
    u16*  Wt2  = (u16*)(ws + alloc(7ull * 1048576 * 2));
    u16*  Wst2 = (u16*)(ws + alloc(1048576ull * 2));

    if (base_off > ws_size) {
        k_zero<<<2048, 256, 0, stream>>>(out, (long)out_size);
        return;
    }
    bool sep = (off <= ws_size);
    if (!sep) { Wt2 = Wt; Wst2 = Wst; }

    (void)hipFuncSetAttribute((const void*)k_gemm8<true, true>,
                              hipFuncAttributeMaxDynamicSharedMemorySize, 131072);
    (void)hipFuncSetAttribute((const void*)k_gemm8<false, false>,
                              hipFuncAttributeMaxDynamicSharedMemorySize, 131072);

    k_prep<<<sep ? 12288 : 8192, 256, 0, stream>>>(
        x, xb, slot_token, zrow, W1, Ws1, Wt, Wst, W2, Ws2, Wt2, Wst2);
    k_router<<<1024, 512, 0, stream>>>(x, Wr, Wn, arO, anO);
    k_tail<<<32, 256, 0, stream>>>(arO, anO, noise, br, bn, idx0, idx1, p0, p1, cntA, sumA);
    k_scanbase<<<1, 256, 0, stream>>>(cntA, sumA, baseA, cnt, out);
    k_assign<<<32, 256, 0, stream>>>(idx0, idx1, baseA, slot_token, ts0, ts1);

    k_gemm8<true, true><<<TB8, 512, 131072, stream>>>(
        xb, xb, slot_token, zrow, Wt, Wst, b1, bs1, He, Hs, cnt);

    if (!sep)
        k_transpose<<<dim3(4, 128, 8), 256, 0, stream>>>(W2, Ws2, Wt, Wst);

    k_gemm8<false, false><<<TB8, 512, 131072, stream>>>(
        He, Hs, nullptr, zrow, Wt2, Wst2, b2, bs2, OutE, Xs, cnt);

    k_combine<<<NTOK, 256, 0, stream>>>(Xs, OutE, ts0, ts1, p0, p1, out);
    (void)in_sizes; (void)n_in; (void)out_size;
}

// Round 4
// 415.321 us; speedup vs baseline: 1.0478x; 1.0297x over previous
//
#include <hip/hip_runtime.h>
#include <math.h>

typedef unsigned short u16;
typedef __attribute__((ext_vector_type(4))) float f32x4;
typedef __attribute__((ext_vector_type(4))) int v4i;
typedef __bf16 bf16x8 __attribute__((ext_vector_type(8)));

#define NTOK 8192
#define DDIM 1024
#define NEXP 7
#define CAPC 2574      /* int(8192*2/7*1.1) */
#define CPAD 2688      /* 21*128 */
#define EBLK 1176      /* 7 experts * 21 mblk * 8 nblk */
#define TBLK 1688      /* + 64*8 shared blocks */

__device__ inline float bf2f(u16 u) {
    union { unsigned int i; float f; } c; c.i = ((unsigned int)u) << 16; return c.f;
}
__device__ inline u16 f2bf(float f) {
    union { float f; unsigned int i; } c; c.f = f;
    unsigned int u = c.i;
    unsigned int r = (u + 0x7fffu + ((u >> 16) & 1u)) >> 16;
    return (u16)r;
}

__device__ inline void gl2lds16(const u16* g, const u16* l) {
    __builtin_amdgcn_global_load_lds(
        (const __attribute__((address_space(1))) unsigned int*)g,
        (__attribute__((address_space(3))) unsigned int*)l, 16, 0, 0);
}

#define SCHED0()  __builtin_amdgcn_sched_barrier(0)
#define PRIO1()   __builtin_amdgcn_s_setprio(1)
#define PRIO0()   __builtin_amdgcn_s_setprio(0)
#define LGKM8()   asm volatile("s_waitcnt lgkmcnt(8)")
#define LGKM0()   asm volatile("s_waitcnt lgkmcnt(0)")

// ---------------- guard: zero the output (ws_size-too-small diagnostic) ----------------
__global__ void k_zero(float* out, long n) {
    long i = (long)blockIdx.x * 256 + threadIdx.x;
    long stride = (long)gridDim.x * 256;
    for (; i < n; i += stride) out[i] = 0.f;
}

// ---------------- LDS-tiled transpose core: 256k x 64n tile, both sides coalesced ----------------
// dst[n*1024+k] = f2bf(src[k*1024+n]); LDS XOR swizzle s(n)=((n>>2)&7)<<3 breaks bank conflicts.
__device__ inline void tile_transpose(const float* __restrict__ src, u16* __restrict__ dst,
                                      int k0, int n0, int tid, u16 (*tbuf)[256]) {
#pragma unroll
    for (int p = 0; p < 16; ++p) {
        int kl = p * 16 + (tid >> 4);
        int nl = (tid & 15) * 4;
        float4 v = *(const float4*)(src + (long)(k0 + kl) * 1024 + n0 + nl);
        int s = (tid & 7) << 3;          /* ((nl>>2)&7)<<3 */
        int kx = kl ^ s;
        tbuf[nl + 0][kx] = f2bf(v.x);
        tbuf[nl + 1][kx] = f2bf(v.y);
        tbuf[nl + 2][kx] = f2bf(v.z);
        tbuf[nl + 3][kx] = f2bf(v.w);
    }
    __syncthreads();
#pragma unroll
    for (int q = 0; q < 8; ++q) {
        int nl = q * 8 + (tid >> 5);
        int kl = (tid & 31) * 8;
        int s = ((nl >> 2) & 7) << 3;
        const u16* pr = &tbuf[nl][kl ^ s];
        ushort4 a = *(const ushort4*)pr;
        ushort4 b = *(const ushort4*)(pr + 4);
        u16* pd = dst + (long)(n0 + nl) * 1024 + k0 + kl;
        *(ushort4*)pd = a;
        *(ushort4*)(pd + 4) = b;
    }
}

// ---------------- fused prep ----------------
// blocks 0..4095: x->bf16 + inits; 4096+: LDS-tiled transposes.
// set0 = {W1(7), Ws1} (blocks 4096..4607); set1 = {W2(7), Ws2} (4608..5119, only when sep).
__global__ void k_prep(const float* __restrict__ x, u16* __restrict__ xb,
                       int* __restrict__ slot_token, u16* __restrict__ zrow,
                       const float* __restrict__ W1, const float* __restrict__ Ws1,
                       u16* __restrict__ Wt, u16* __restrict__ Wst,
                       const float* __restrict__ W2, const float* __restrict__ Ws2,
                       u16* __restrict__ Wt2, u16* __restrict__ Wst2) {
    __shared__ u16 tbuf[64][256];
    int bid = blockIdx.x, tid = threadIdx.x;
    if (bid < 4096) {
        int gid = bid * 256 + tid;
        int i = gid * 8;
        float4 a = *(const float4*)(x + i);
        float4 b = *(const float4*)(x + i + 4);
        ushort4 o0; o0.x = f2bf(a.x); o0.y = f2bf(a.y); o0.z = f2bf(a.z); o0.w = f2bf(a.w);
        ushort4 o1; o1.x = f2bf(b.x); o1.y = f2bf(b.y); o1.z = f2bf(b.z); o1.w = f2bf(b.w);
        *(ushort4*)(xb + i) = o0;
        *(ushort4*)(xb + i + 4) = o1;
        if (gid < DDIM) zrow[gid] = 0;
        if (gid < NEXP * CPAD) slot_token[gid] = NTOK;
        return;
    }
    int tb = bid - 4096;
    int set = tb >> 9;          /* 0 or 1 */
    int t9 = tb & 511;
    int z = t9 >> 6;            /* matrix 0..7 */
    int rem = t9 & 63;
    int k0 = (rem >> 4) * 256;
    int n0 = (rem & 15) * 64;
    const float* srcE = set ? W2 : W1;
    const float* srcS = set ? Ws2 : Ws1;
    u16* dE = set ? Wt2 : Wt;
    u16* dS = set ? Wst2 : Wst;
    const float* src; u16* dst;
    if (z < 7) { src = srcE + (long)z * 1048576; dst = dE + (long)z * 1048576; }
    else       { src = srcS;                     dst = dS; }
    tile_transpose(src, dst, k0, n0, tid, tbuf);
}

// ---------------- weight transpose phase 2 (fallback when !sep): set1 only ----------------
__global__ void k_transpose(const float* __restrict__ srcE, const float* __restrict__ srcS,
                            u16* __restrict__ Wt, u16* __restrict__ Wst) {
    __shared__ u16 tbuf[64][256];
    int bid = blockIdx.x, tid = threadIdx.x;
    int z = bid >> 6;
    int rem = bid & 63;
    int k0 = (rem >> 4) * 256;
    int n0 = (rem & 15) * 64;
    const float* src; u16* dst;
    if (z < 7) { src = srcE + (long)z * 1048576; dst = Wt + (long)z * 1048576; }
    else       { src = srcS;                     dst = Wst; }
    tile_transpose(src, dst, k0, n0, tid, tbuf);
}

// ---------------- router main: fp64 dot-products only (no libm -> low VGPR) ----------------
__global__ __launch_bounds__(512) void k_router(
    const float* __restrict__ x,
    const float* __restrict__ Wr, const float* __restrict__ Wn,
    double* __restrict__ arO, double* __restrict__ anO) {
    __shared__ float swr[7168];
    __shared__ float swn[7168];
    int tid = threadIdx.x;
    for (int i = tid; i < 7168; i += 512) { swr[i] = Wr[i]; swn[i] = Wn[i]; }
    __syncthreads();
    int lane = tid & 63, wv = tid >> 6;
    int t = blockIdx.x * 8 + wv;
    double ar[7] = {0,0,0,0,0,0,0}, an[7] = {0,0,0,0,0,0,0};
    for (int j = 0; j < 16; ++j) {
        int d = j * 64 + lane;
        double xd = (double)x[t * 1024 + d];
#pragma unroll
        for (int e = 0; e < 7; ++e) {
            ar[e] += xd * (double)swr[d * 7 + e];
            an[e] += xd * (double)swn[d * 7 + e];
        }
    }
#pragma unroll
    for (int e = 0; e < 7; ++e) {
        for (int o = 32; o > 0; o >>= 1) {
            ar[e] += __shfl_xor(ar[e], o);
            an[e] += __shfl_xor(an[e], o);
        }
    }
    if (lane == 0) {
#pragma unroll
        for (int e = 0; e < 7; ++e) { arO[t * 7 + e] = ar[e]; anO[t * 7 + e] = an[e]; }
    }
}

// ---------------- router tail + count ----------------
__global__ void k_tail(const double* __restrict__ arO, const double* __restrict__ anO,
                       const float* __restrict__ noise,
                       const float* __restrict__ br, const float* __restrict__ bn,
                       int* __restrict__ idx0, int* __restrict__ idx1,
                       float* __restrict__ p0, float* __restrict__ p1,
                       int* __restrict__ cntA, double* __restrict__ sumA) {
    int t = blockIdx.x * 256 + threadIdx.x;
    int lane = threadIdx.x & 63;
    double best = -1e300, second = -1e300; int b0 = 0, b1 = 0;
#pragma unroll
    for (int e = 0; e < 7; ++e) {
        double lg = arO[t * 7 + e] + (double)br[e];
        double z  = anO[t * 7 + e] + (double)bn[e];
        double sp = (z > 30.0) ? (z + log1p(exp(-z))) : log1p(exp(z));
        double v  = lg + (double)noise[t * 7 + e] * sp;
        if (v > best)        { second = best; b1 = b0; best = v; b0 = e; }
        else if (v > second) { second = v; b1 = e; }
    }
    double ex = exp(second - best);
    float q0 = (float)(1.0 / (1.0 + ex));
    float q1 = (float)(ex / (1.0 + ex));
    idx0[t] = b0; idx1[t] = b1; p0[t] = q0; p1[t] = q1;
    int chunk = t >> 6;
    double dq0 = (double)q0, dq1 = (double)q1;
#pragma unroll
    for (int e = 0; e < 7; ++e) {
        unsigned long long m = __ballot((b0 == e) || (b1 == e));
        double q = (b0 == e ? dq0 : 0.0) + (b1 == e ? dq1 : 0.0);
        for (int o = 32; o > 0; o >>= 1) q += __shfl_xor(q, o);
        if (lane == 0) { cntA[e * 128 + chunk] = __popcll(m); sumA[e * 128 + chunk] = q; }
    }
}

// ---------------- phase B: exclusive scan (7 experts in parallel) + lbl ----------------
__global__ void k_scanbase(const int* __restrict__ cntA, const double* __restrict__ sumA,
                           int* __restrict__ baseA, int* __restrict__ cnt,
                           float* __restrict__ out) {
    __shared__ int s[7][128];
    __shared__ double rd[7][128];
    __shared__ int rawc[7];
    __shared__ double ps[7];
    int tid = threadIdx.x;            /* 896 threads: e = tid>>7, i = tid&127 */
    int e = tid >> 7, i = tid & 127;
    int v = cntA[e * 128 + i];
    s[e][i] = v;
    rd[e][i] = sumA[e * 128 + i];
    __syncthreads();
    for (int o = 1; o < 128; o <<= 1) {
        int add = (i >= o) ? s[e][i - o] : 0;
        __syncthreads();
        s[e][i] += add;
        __syncthreads();
    }
    baseA[e * 128 + i] = s[e][i] - v;
    if (i == 127) { rawc[e] = s[e][127]; cnt[e] = (s[e][127] < CAPC) ? s[e][127] : CAPC; }
    for (int o = 64; o > 0; o >>= 1) {
        if (i < o) rd[e][i] += rd[e][i + o];
        __syncthreads();
    }
    if (i == 0) ps[e] = rd[e][0];
    __syncthreads();
    if (tid == 0) {
        double acc = 0.0;
        for (int ee = 0; ee < 7; ++ee) acc += ps[ee] * (double)rawc[ee];
        out[(long)NTOK * DDIM] = (float)(7.0 * acc / (8192.0 * 8192.0));
    }
}

// ---------------- phase C: slot assignment (FCFS, capacity-dropped) ----------------
__global__ void k_assign(const int* __restrict__ idx0, const int* __restrict__ idx1,
                         const int* __restrict__ baseA, int* __restrict__ slot_token,
                         int* __restrict__ ts0, int* __restrict__ ts1) {
    int lane = threadIdx.x & 63;
    int chunk = (blockIdx.x * 256 + threadIdx.x) >> 6;
    int t = chunk * 64 + lane;
    int i0 = idx0[t], i1 = idx1[t];
    int myts0 = -1, myts1 = -1;
    unsigned long long lt = (1ull << lane) - 1ull;
#pragma unroll
    for (int e = 0; e < 7; ++e) {
        bool has = (i0 == e) || (i1 == e);
        unsigned long long m = __ballot(has);
        int pre = __popcll(m & lt);
        int pos = baseA[e * 128 + chunk] + pre;
        if (has && pos < CAPC) {
            int slot = e * CPAD + pos;
            slot_token[slot] = t;
            if (i0 == e) myts0 = slot; else myts1 = slot;
        }
    }
    ts0[t] = myts0; ts1[t] = myts1;
}

// ============ 128x128 MFMA GEMM, 2-phase double-buffer (T3 minimum recipe) ============
// Round-0 structure + dbuf: stage tile T+1 BEFORE computing tile T; single __syncthreads
// per K-tile AFTER compute (its implicit vmcnt(0) drain is covered by ~1300cy of work).
// Fragment reads are compiler-opaque asm ds_read_b128 with static buffer indices so no
// aliasing-based vmcnt drain can be inserted before them (rounds 1-3 post-mortem).

union Fr { v4i i; bf16x8 h; };

#define DSR(DST, ADDR, OFF) \
    asm volatile("ds_read_b128 %0, %1 offset:%c2" : "=v"(DST) : "v"(ADDR), "i"(OFF));

// read all 16 fragments of buffer BUF: af0/bf0 (ks=0) first 8, af1/bf1 (ks=1) last 8
#define RDQ(BUF)                                              \
    _Pragma("unroll")                                         \
    for (int mi = 0; mi < 4; ++mi) { DSR(af0[mi].i, aA0, (BUF) * 16384 + mi * 2048) } \
    _Pragma("unroll")                                         \
    for (int ni = 0; ni < 4; ++ni) { DSR(bf0[ni].i, aB0, (BUF) * 16384 + ni * 2048) } \
    _Pragma("unroll")                                         \
    for (int mi = 0; mi < 4; ++mi) { DSR(af1[mi].i, aA1, (BUF) * 16384 + mi * 2048) } \
    _Pragma("unroll")                                         \
    for (int ni = 0; ni < 4; ++ni) { DSR(bf1[ni].i, aB1, (BUF) * 16384 + ni * 2048) }

#define MFMAS(AF, BF)                                         \
    _Pragma("unroll")                                         \
    for (int mi = 0; mi < 4; ++mi)                            \
        _Pragma("unroll")                                     \
        for (int ni = 0; ni < 4; ++ni)                        \
            acc[mi][ni] = __builtin_amdgcn_mfma_f32_16x16x32_bf16( \
                AF[mi].h, BF[ni].h, acc[mi][ni], 0, 0, 0);

#define STG(BUF, K)                                           \
    _Pragma("unroll")                                         \
    for (int i = 0; i < 4; ++i) {                             \
        gl2lds16(arow[i] + (K) + kgs * 8, &ldsA[BUF][(wv * 4 + i) * 512]); \
        gl2lds16(brow[i] + (K) + kgs * 8, &ldsB[BUF][(wv * 4 + i) * 512]); \
    }

template <bool GATHER, bool MODE_H>
__global__ __launch_bounds__(256) void k_gemm(
    const u16* __restrict__ AbaseE, const u16* __restrict__ AbaseS,
    const int* __restrict__ gidx, const u16* __restrict__ zrow,
    const u16* __restrict__ WtE, const u16* __restrict__ WtS,
    const float* __restrict__ biasE, const float* __restrict__ biasS,
    u16* __restrict__ outE, u16* __restrict__ outS,
    const int* __restrict__ cnt) {
    __shared__ __align__(16) u16 ldsA[2][8192];
    __shared__ __align__(16) u16 ldsB[2][8192];
    int bid = blockIdx.x;
    int tid = threadIdx.x, lane = tid & 63, wv = tid >> 6;
    int lrow = lane >> 3, lkg = lane & 7;
    int kgs = lkg ^ lrow;

    int e = 0, my, nx;
    const u16* Ab; const u16* Bb; const float* bias; u16* outp;
    bool gather = false;
    if (bid < EBLK) {
        e = bid / 168; int r = bid % 168; my = r >> 3; nx = r & 7;
        if (my * 128 >= cnt[e]) return;
        Ab = AbaseE + (GATHER ? 0L : (long)e * CPAD * 1024);
        Bb = WtE + ((long)e << 20);
        bias = biasE + e * 1024;
        outp = outE + (long)e * CPAD * 1024;
        gather = GATHER;
    } else {
        int sb = bid - EBLK; my = sb >> 3; nx = sb & 7;
        Ab = AbaseS; Bb = WtS; bias = biasS; outp = outS;
    }
    int m0 = my * 128, n0 = nx * 128;

    const u16* arow[4];
    const u16* brow[4];
#pragma unroll
    for (int i = 0; i < 4; ++i) {
        int r = (wv * 4 + i) * 8 + lrow;     // 0..127
        if (gather) {
            int tok = gidx[e * CPAD + m0 + r];
            arow[i] = (tok < NTOK) ? (AbaseE + (long)tok * DDIM) : zrow;
        } else {
            arow[i] = Ab + (long)(m0 + r) * DDIM;
        }
        brow[i] = Bb + (long)(n0 + r) * DDIM;
    }
    f32x4 acc[4][4];
#pragma unroll
    for (int a = 0; a < 4; ++a)
#pragma unroll
        for (int b = 0; b < 4; ++b) { f32x4 z = {0.f, 0.f, 0.f, 0.f}; acc[a][b] = z; }

    int wm = (wv >> 1) * 64, wn = (wv & 1) * 64;
    int rl = lane & 15, quad = lane >> 4, kq7 = rl & 7;

    // asm ds_read byte addresses (row-major [row][64] u16 tiles, XOR-(row&7) swizzle)
    unsigned bA = (unsigned)(uintptr_t)(__attribute__((address_space(3))) u16*)&ldsA[0][0];
    unsigned bB = (unsigned)(uintptr_t)(__attribute__((address_space(3))) u16*)&ldsB[0][0];
    int sw0 = ((quad ^ kq7) & 7) * 16;
    int aA0 = (int)bA + (wm + rl) * 128 + sw0;   // ks=0
    int aA1 = aA0 ^ 64;                          // ks=1: (quad+4)^kq7 toggles bit2 -> ^64 bytes
    int aB0 = (int)bB + (wn + rl) * 128 + sw0;
    int aB1 = aB0 ^ 64;

    Fr af0[4], af1[4], bf0[4], bf1[4];

    // prologue: stage tile k=0 into buf0
    STG(0, 0)
    __syncthreads();

    for (int tt = 0; tt < 8; ++tt) {
        int kc = tt * 128;
        // ---- half 0: compute buf0 (tile kc); stage tile kc+64 -> buf1 (hidden under compute)
        STG(1, kc + 64)
        RDQ(0)
        LGKM8(); SCHED0();
        PRIO1(); MFMAS(af0, bf0) PRIO0();
        LGKM0(); SCHED0();
        PRIO1(); MFMAS(af1, bf1) PRIO0();
        __syncthreads();   // vmcnt(0)+lgkm drain: buf1 staged, buf0 reads done
        // ---- half 1: compute buf1 (tile kc+64); stage tile kc+128 -> buf0
        if (tt < 7) {
            STG(0, kc + 128)
        }
        RDQ(1)
        LGKM8(); SCHED0();
        PRIO1(); MFMAS(af0, bf0) PRIO0();
        LGKM0(); SCHED0();
        PRIO1(); MFMAS(af1, bf1) PRIO0();
        __syncthreads();
    }

    // epilogue: C/D layout col = lane&15, row = quad*4 + reg (identical to round-0)
#pragma unroll
    for (int ni = 0; ni < 4; ++ni) {
        int col = n0 + wn + ni * 16 + rl;
        float bv = bias[col];
#pragma unroll
        for (int mi = 0; mi < 4; ++mi) {
            int rowb = m0 + wm + mi * 16 + quad * 4;
#pragma unroll
            for (int r = 0; r < 4; ++r) {
                float v = acc[mi][ni][r] + bv;
                if constexpr (MODE_H) v = v > 0.f ? v : 0.f;
                outp[(long)(rowb + r) * DDIM + col] = f2bf(v);
            }
        }
    }
}

// ---------------- combine: out = Xs + g0*OutE[s0] + g1*OutE[s1] ----------------
__global__ __launch_bounds__(256) void k_combine(
    const u16* __restrict__ Xs, const u16* __restrict__ OutE,
    const int* __restrict__ ts0, const int* __restrict__ ts1,
    const float* __restrict__ p0, const float* __restrict__ p1,
    float* __restrict__ out) {
    int b = blockIdx.x;
    int d = threadIdx.x * 4;
    long base = (long)b * DDIM + d;
    ushort4 xs4 = *(const ushort4*)(Xs + base);
    float r0 = bf2f(xs4.x), r1 = bf2f(xs4.y), r2 = bf2f(xs4.z), r3 = bf2f(xs4.w);
    int s0 = ts0[b], s1 = ts1[b];
    if (s0 >= 0) {
        float g = p0[b];
        ushort4 o4 = *(const ushort4*)(OutE + (long)s0 * DDIM + d);
        r0 += g * bf2f(o4.x); r1 += g * bf2f(o4.y); r2 += g * bf2f(o4.z); r3 += g * bf2f(o4.w);
    }
    if (s1 >= 0) {
        float g = p1[b];
        ushort4 o4 = *(const ushort4*)(OutE + (long)s1 * DDIM + d);
        r0 += g * bf2f(o4.x); r1 += g * bf2f(o4.y); r2 += g * bf2f(o4.z); r3 += g * bf2f(o4.w);
    }
    float4 w; w.x = r0; w.y = r1; w.z = r2; w.w = r3;
    *(float4*)(out + base) = w;
}

extern "C" void kernel_launch(void* const* d_in, const int* in_sizes, int n_in,
                              void* d_out, int out_size, void* d_ws, size_t ws_size,
                              hipStream_t stream) {
    const float* x    = (const float*)d_in[0];
    const float* noise= (const float*)d_in[1];
    const float* Wr   = (const float*)d_in[2];
    const float* br   = (const float*)d_in[3];
    const float* Wn   = (const float*)d_in[4];
    const float* bn   = (const float*)d_in[5];
    const float* W1   = (const float*)d_in[6];
    const float* b1   = (const float*)d_in[7];
    const float* W2   = (const float*)d_in[8];
    const float* b2   = (const float*)d_in[9];
    const float* Ws1  = (const float*)d_in[10];
    const float* bs1  = (const float*)d_in[11];
    const float* Ws2  = (const float*)d_in[12];
    const float* bs2  = (const float*)d_in[13];
    float* out = (float*)d_out;
    char* ws = (char*)d_ws;

    size_t off = 0;
    auto alloc = [&](size_t bytes) { size_t o = off; off += (bytes + 255) & ~(size_t)255; return o; };
    u16*  Wt   = (u16*)(ws + alloc(7ull * 1048576 * 2));
    u16*  Wst  = (u16*)(ws + alloc(1048576ull * 2));
    u16*  xb   = (u16*)(ws + alloc((size_t)NTOK * 1024 * 2));
    u16*  He   = (u16*)(ws + alloc((size_t)NEXP * CPAD * 1024 * 2));
    u16*  Hs   = (u16*)(ws + alloc((size_t)NTOK * 1024 * 2));
    u16*  OutE = (u16*)(ws + alloc((size_t)NEXP * CPAD * 1024 * 2));
    u16*  Xs   = (u16*)(ws + alloc((size_t)NTOK * 1024 * 2));
    int*  idx0 = (int*)(ws + alloc(NTOK * 4));
    int*  idx1 = (int*)(ws + alloc(NTOK * 4));
    float* p0  = (float*)(ws + alloc(NTOK * 4));
    float* p1  = (float*)(ws + alloc(NTOK * 4));
    int*  ts0  = (int*)(ws + alloc(NTOK * 4));
    int*  ts1  = (int*)(ws + alloc(NTOK * 4));
    int*  slot_token = (int*)(ws + alloc(NEXP * CPAD * 4));
    int*  cntA = (int*)(ws + alloc(7 * 128 * 4));
    int*  baseA= (int*)(ws + alloc(7 * 128 * 4));
    double* sumA = (double*)(ws + alloc(7 * 128 * 8));
    int*  cnt    = (int*)(ws + alloc(8 * 4));
    u16*  zrow   = (u16*)(ws + alloc(1024 * 2));
    double* arO  = (double*)(ws + alloc((size_t)NTOK * 7 * 8));
    double* anO  = (double*)(ws + alloc((size_t)NTOK * 7 * 8));
    size_t base_off = off;
    // optional separate phase-2 transpose buffers (removes mid-pipeline bubble)
    u16*  Wt2  = (u16*)(ws + alloc(7ull * 1048576 * 2));
    u16*  Wst2 = (u16*)(ws + alloc(1048576ull * 2));

    if (base_off > ws_size) {
        k_zero<<<2048, 256, 0, stream>>>(out, (long)out_size);
        return;
    }
    bool sep = (off <= ws_size);
    if (!sep) { Wt2 = Wt; Wst2 = Wst; }

    // fused: x->bf16 + inits + transpose set0 (+ set1 when sep)
    k_prep<<<sep ? 5120 : 4608, 256, 0, stream>>>(
        x, xb, slot_token, zrow, W1, Ws1, Wt, Wst, W2, Ws2, Wt2, Wst2);
    k_router<<<1024, 512, 0, stream>>>(x, Wr, Wn, arO, anO);
    k_tail<<<32, 256, 0, stream>>>(arO, anO, noise, br, bn, idx0, idx1, p0, p1, cntA, sumA);
    k_scanbase<<<1, 896, 0, stream>>>(cntA, sumA, baseA, cnt, out);
    k_assign<<<32, 256, 0, stream>>>(idx0, idx1, baseA, slot_token, ts0, ts1);

    // fused layer 1: experts (gather xb via slot_token) + shared, relu -> bf16 He/Hs
    k_gemm<true, true><<<TBLK, 256, 0, stream>>>(
        xb, xb, slot_token, zrow, Wt, Wst, b1, bs1, He, Hs, cnt);

    if (!sep)   // fallback: set1 transpose between the GEMMs
        k_transpose<<<512, 256, 0, stream>>>(W2, Ws2, Wt, Wst);

    // fused layer 2: -> bf16 OutE/Xs (+b2/bs2)
    k_gemm<false, false><<<TBLK, 256, 0, stream>>>(
        He, Hs, nullptr, zrow, Wt2, Wst2, b2, bs2, OutE, Xs, cnt);

    k_combine<<<NTOK, 256, 0, stream>>>(Xs, OutE, ts0, ts1, p0, p1, out);
    (void)in_sizes; (void)n_in; (void)out_size;
}

// Round 5
// 386.143 us; speedup vs baseline: 1.1270x; 1.0756x over previous
//
#include <hip/hip_runtime.h>
#include <math.h>

typedef unsigned short u16;
typedef __attribute__((ext_vector_type(4))) float f32x4;
typedef __bf16 bf16x8 __attribute__((ext_vector_type(8)));

#define NTOK 8192
#define DDIM 1024
#define NEXP 7
#define CAPC 2574      /* int(8192*2/7*1.1) */
#define CPAD 2688      /* 21*128 */
#define EBLK 1176      /* 7 experts * 21 mblk * 8 nblk */
#define TBLK 1688      /* + 64*8 shared blocks */

__device__ inline float bf2f(u16 u) {
    union { unsigned int i; float f; } c; c.i = ((unsigned int)u) << 16; return c.f;
}
__device__ inline u16 f2bf(float f) {
    union { float f; unsigned int i; } c; c.f = f;
    unsigned int u = c.i;
    unsigned int r = (u + 0x7fffu + ((u >> 16) & 1u)) >> 16;
    return (u16)r;
}

__device__ inline void gl2lds16(const u16* g, const u16* l) {
    __builtin_amdgcn_global_load_lds(
        (const __attribute__((address_space(1))) unsigned int*)g,
        (__attribute__((address_space(3))) unsigned int*)l, 16, 0, 0);
}

// ---------------- guard: zero the output (ws_size-too-small diagnostic) ----------------
__global__ void k_zero(float* out, long n) {
    long i = (long)blockIdx.x * 256 + threadIdx.x;
    long stride = (long)gridDim.x * 256;
    for (; i < n; i += stride) out[i] = 0.f;
}

// ---------------- LDS-tiled transpose core: 256k x 64n tile, both sides coalesced ----------------
// dst[n*1024+k] = f2bf(src[k*1024+n]); LDS XOR swizzle s(n)=((n>>2)&7)<<3 breaks bank conflicts.
__device__ inline void tile_transpose(const float* __restrict__ src, u16* __restrict__ dst,
                                      int k0, int n0, int tid, u16 (*tbuf)[256]) {
#pragma unroll
    for (int p = 0; p < 16; ++p) {
        int kl = p * 16 + (tid >> 4);
        int nl = (tid & 15) * 4;
        float4 v = *(const float4*)(src + (long)(k0 + kl) * 1024 + n0 + nl);
        int s = (tid & 7) << 3;          /* ((nl>>2)&7)<<3 */
        int kx = kl ^ s;
        tbuf[nl + 0][kx] = f2bf(v.x);
        tbuf[nl + 1][kx] = f2bf(v.y);
        tbuf[nl + 2][kx] = f2bf(v.z);
        tbuf[nl + 3][kx] = f2bf(v.w);
    }
    __syncthreads();
#pragma unroll
    for (int q = 0; q < 8; ++q) {
        int nl = q * 8 + (tid >> 5);
        int kl = (tid & 31) * 8;
        int s = ((nl >> 2) & 7) << 3;
        const u16* pr = &tbuf[nl][kl ^ s];
        ushort4 a = *(const ushort4*)pr;
        ushort4 b = *(const ushort4*)(pr + 4);
        u16* pd = dst + (long)(n0 + nl) * 1024 + k0 + kl;
        *(ushort4*)pd = a;
        *(ushort4*)(pd + 4) = b;
    }
}

// ---------------- fused prep ----------------
// blocks 0..4095: x->bf16 + inits; 4096+: LDS-tiled transposes.
// set0 = {W1(7), Ws1} (blocks 4096..4607); set1 = {W2(7), Ws2} (4608..5119, only when sep).
__global__ void k_prep(const float* __restrict__ x, u16* __restrict__ xb,
                       int* __restrict__ slot_token, u16* __restrict__ zrow,
                       const float* __restrict__ W1, const float* __restrict__ Ws1,
                       u16* __restrict__ Wt, u16* __restrict__ Wst,
                       const float* __restrict__ W2, const float* __restrict__ Ws2,
                       u16* __restrict__ Wt2, u16* __restrict__ Wst2) {
    __shared__ u16 tbuf[64][256];
    int bid = blockIdx.x, tid = threadIdx.x;
    if (bid < 4096) {
        int gid = bid * 256 + tid;
        int i = gid * 8;
        float4 a = *(const float4*)(x + i);
        float4 b = *(const float4*)(x + i + 4);
        ushort4 o0; o0.x = f2bf(a.x); o0.y = f2bf(a.y); o0.z = f2bf(a.z); o0.w = f2bf(a.w);
        ushort4 o1; o1.x = f2bf(b.x); o1.y = f2bf(b.y); o1.z = f2bf(b.z); o1.w = f2bf(b.w);
        *(ushort4*)(xb + i) = o0;
        *(ushort4*)(xb + i + 4) = o1;
        if (gid < DDIM) zrow[gid] = 0;
        if (gid < NEXP * CPAD) slot_token[gid] = NTOK;
        return;
    }
    int tb = bid - 4096;
    int set = tb >> 9;          /* 0 or 1 */
    int t9 = tb & 511;
    int z = t9 >> 6;            /* matrix 0..7 */
    int rem = t9 & 63;
    int k0 = (rem >> 4) * 256;
    int n0 = (rem & 15) * 64;
    const float* srcE = set ? W2 : W1;
    const float* srcS = set ? Ws2 : Ws1;
    u16* dE = set ? Wt2 : Wt;
    u16* dS = set ? Wst2 : Wst;
    const float* src; u16* dst;
    if (z < 7) { src = srcE + (long)z * 1048576; dst = dE + (long)z * 1048576; }
    else       { src = srcS;                     dst = dS; }
    tile_transpose(src, dst, k0, n0, tid, tbuf);
}

// ---------------- weight transpose phase 2 (fallback when !sep): set1 only ----------------
__global__ void k_transpose(const float* __restrict__ srcE, const float* __restrict__ srcS,
                            u16* __restrict__ Wt, u16* __restrict__ Wst) {
    __shared__ u16 tbuf[64][256];
    int bid = blockIdx.x, tid = threadIdx.x;
    int z = bid >> 6;
    int rem = bid & 63;
    int k0 = (rem >> 4) * 256;
    int n0 = (rem & 15) * 64;
    const float* src; u16* dst;
    if (z < 7) { src = srcE + (long)z * 1048576; dst = Wt + (long)z * 1048576; }
    else       { src = srcS;                     dst = Wst; }
    tile_transpose(src, dst, k0, n0, tid, tbuf);
}

// ---------------- router main: fp64 dot-products only (no libm -> low VGPR) ----------------
__global__ __launch_bounds__(512) void k_router(
    const float* __restrict__ x,
    const float* __restrict__ Wr, const float* __restrict__ Wn,
    double* __restrict__ arO, double* __restrict__ anO) {
    __shared__ float swr[7168];
    __shared__ float swn[7168];
    int tid = threadIdx.x;
    for (int i = tid; i < 7168; i += 512) { swr[i] = Wr[i]; swn[i] = Wn[i]; }
    __syncthreads();
    int lane = tid & 63, wv = tid >> 6;
    int t = blockIdx.x * 8 + wv;
    double ar[7] = {0,0,0,0,0,0,0}, an[7] = {0,0,0,0,0,0,0};
    for (int j = 0; j < 16; ++j) {
        int d = j * 64 + lane;
        double xd = (double)x[t * 1024 + d];
#pragma unroll
        for (int e = 0; e < 7; ++e) {
            ar[e] += xd * (double)swr[d * 7 + e];
            an[e] += xd * (double)swn[d * 7 + e];
        }
    }
#pragma unroll
    for (int e = 0; e < 7; ++e) {
        for (int o = 32; o > 0; o >>= 1) {
            ar[e] += __shfl_xor(ar[e], o);
            an[e] += __shfl_xor(an[e], o);
        }
    }
    if (lane == 0) {
#pragma unroll
        for (int e = 0; e < 7; ++e) { arO[t * 7 + e] = ar[e]; anO[t * 7 + e] = an[e]; }
    }
}

// ---------------- router tail + count ----------------
__global__ void k_tail(const double* __restrict__ arO, const double* __restrict__ anO,
                       const float* __restrict__ noise,
                       const float* __restrict__ br, const float* __restrict__ bn,
                       int* __restrict__ idx0, int* __restrict__ idx1,
                       float* __restrict__ p0, float* __restrict__ p1,
                       int* __restrict__ cntA, double* __restrict__ sumA) {
    int t = blockIdx.x * 256 + threadIdx.x;
    int lane = threadIdx.x & 63;
    double best = -1e300, second = -1e300; int b0 = 0, b1 = 0;
#pragma unroll
    for (int e = 0; e < 7; ++e) {
        double lg = arO[t * 7 + e] + (double)br[e];
        double z  = anO[t * 7 + e] + (double)bn[e];
        double sp = (z > 30.0) ? (z + log1p(exp(-z))) : log1p(exp(z));
        double v  = lg + (double)noise[t * 7 + e] * sp;
        if (v > best)        { second = best; b1 = b0; best = v; b0 = e; }
        else if (v > second) { second = v; b1 = e; }
    }
    double ex = exp(second - best);
    float q0 = (float)(1.0 / (1.0 + ex));
    float q1 = (float)(ex / (1.0 + ex));
    idx0[t] = b0; idx1[t] = b1; p0[t] = q0; p1[t] = q1;
    int chunk = t >> 6;
    double dq0 = (double)q0, dq1 = (double)q1;
#pragma unroll
    for (int e = 0; e < 7; ++e) {
        unsigned long long m = __ballot((b0 == e) || (b1 == e));
        double q = (b0 == e ? dq0 : 0.0) + (b1 == e ? dq1 : 0.0);
        for (int o = 32; o > 0; o >>= 1) q += __shfl_xor(q, o);
        if (lane == 0) { cntA[e * 128 + chunk] = __popcll(m); sumA[e * 128 + chunk] = q; }
    }
}

// ---------------- phase B: exclusive scan (7 experts in parallel) + lbl ----------------
__global__ void k_scanbase(const int* __restrict__ cntA, const double* __restrict__ sumA,
                           int* __restrict__ baseA, int* __restrict__ cnt,
                           float* __restrict__ out) {
    __shared__ int s[7][128];
    __shared__ double rd[7][128];
    __shared__ int rawc[7];
    __shared__ double ps[7];
    int tid = threadIdx.x;            /* 896 threads: e = tid>>7, i = tid&127 */
    int e = tid >> 7, i = tid & 127;
    int v = cntA[e * 128 + i];
    s[e][i] = v;
    rd[e][i] = sumA[e * 128 + i];
    __syncthreads();
    for (int o = 1; o < 128; o <<= 1) {
        int add = (i >= o) ? s[e][i - o] : 0;
        __syncthreads();
        s[e][i] += add;
        __syncthreads();
    }
    baseA[e * 128 + i] = s[e][i] - v;
    if (i == 127) { rawc[e] = s[e][127]; cnt[e] = (s[e][127] < CAPC) ? s[e][127] : CAPC; }
    for (int o = 64; o > 0; o >>= 1) {
        if (i < o) rd[e][i] += rd[e][i + o];
        __syncthreads();
    }
    if (i == 0) ps[e] = rd[e][0];
    __syncthreads();
    if (tid == 0) {
        double acc = 0.0;
        for (int ee = 0; ee < 7; ++ee) acc += ps[ee] * (double)rawc[ee];
        out[(long)NTOK * DDIM] = (float)(7.0 * acc / (8192.0 * 8192.0));
    }
}

// ---------------- phase C: slot assignment (FCFS, capacity-dropped) ----------------
__global__ void k_assign(const int* __restrict__ idx0, const int* __restrict__ idx1,
                         const int* __restrict__ baseA, int* __restrict__ slot_token,
                         int* __restrict__ ts0, int* __restrict__ ts1) {
    int lane = threadIdx.x & 63;
    int chunk = (blockIdx.x * 256 + threadIdx.x) >> 6;
    int t = chunk * 64 + lane;
    int i0 = idx0[t], i1 = idx1[t];
    int myts0 = -1, myts1 = -1;
    unsigned long long lt = (1ull << lane) - 1ull;
#pragma unroll
    for (int e = 0; e < 7; ++e) {
        bool has = (i0 == e) || (i1 == e);
        unsigned long long m = __ballot(has);
        int pre = __popcll(m & lt);
        int pos = baseA[e * 128 + chunk] + pre;
        if (has && pos < CAPC) {
            int slot = e * CPAD + pos;
            slot_token[slot] = t;
            if (i0 == e) myts0 = slot; else myts1 = slot;
        }
    }
    ts0[t] = myts0; ts1[t] = myts1;
}

// ---------------- fused MFMA GEMM (round-0 structure: occupancy-overlapped) ----------------
// 128x128 tile, BK=64, global_load_lds width-16 staging, 32 KiB LDS -> 3+ blocks/CU.
// Cross-block co-residency hides the staging drain; do NOT add dbuf (r4: -25%).
template <bool GATHER, bool MODE_H>
__global__ __launch_bounds__(256) void k_gemm(
    const u16* __restrict__ AbaseE, const u16* __restrict__ AbaseS,
    const int* __restrict__ gidx, const u16* __restrict__ zrow,
    const u16* __restrict__ WtE, const u16* __restrict__ WtS,
    const float* __restrict__ biasE, const float* __restrict__ biasS,
    u16* __restrict__ outE, u16* __restrict__ outS,
    const int* __restrict__ cnt) {
    __shared__ __align__(16) u16 ldsA[128 * 64];
    __shared__ __align__(16) u16 ldsB[128 * 64];
    int bid = blockIdx.x;
    int tid = threadIdx.x, lane = tid & 63, wv = tid >> 6;
    int lrow = lane >> 3, lkg = lane & 7;
    int kgs = lkg ^ lrow;

    int e = 0, my, nx;
    const u16* Ab; const u16* Bb; const float* bias; u16* outp;
    bool gather = false;
    if (bid < EBLK) {
        e = bid / 168; int r = bid % 168; my = r >> 3; nx = r & 7;
        if (my * 128 >= cnt[e]) return;
        Ab = AbaseE + (GATHER ? 0L : (long)e * CPAD * 1024);
        Bb = WtE + ((long)e << 20);
        bias = biasE + e * 1024;
        outp = outE + (long)e * CPAD * 1024;
        gather = GATHER;
    } else {
        int sb = bid - EBLK; my = sb >> 3; nx = sb & 7;
        Ab = AbaseS; Bb = WtS; bias = biasS; outp = outS;
    }
    int m0 = my * 128, n0 = nx * 128;

    const u16* arow[4];
    const u16* brow[4];
#pragma unroll
    for (int i = 0; i < 4; ++i) {
        int r = (wv * 4 + i) * 8 + lrow;     // 0..127
        if (gather) {
            int tok = gidx[e * CPAD + m0 + r];
            arow[i] = (tok < NTOK) ? (AbaseE + (long)tok * DDIM) : zrow;
        } else {
            arow[i] = Ab + (long)(m0 + r) * DDIM;
        }
        brow[i] = Bb + (long)(n0 + r) * DDIM;
    }
    f32x4 acc[4][4];
#pragma unroll
    for (int a = 0; a < 4; ++a)
#pragma unroll
        for (int b = 0; b < 4; ++b) { f32x4 z = {0.f, 0.f, 0.f, 0.f}; acc[a][b] = z; }

    int wm = (wv >> 1) * 64, wn = (wv & 1) * 64;
    int rl = lane & 15, quad = lane >> 4;

    for (int k0 = 0; k0 < 1024; k0 += 64) {
#pragma unroll
        for (int i = 0; i < 4; ++i) {
            gl2lds16(arow[i] + k0 + kgs * 8, &ldsA[(wv * 4 + i) * 512]);
            gl2lds16(brow[i] + k0 + kgs * 8, &ldsB[(wv * 4 + i) * 512]);
        }
        __syncthreads();   // drains vmcnt -> staged tile visible
#pragma unroll
        for (int ks = 0; ks < 2; ++ks) {
            int kg = ks * 4 + quad;
            bf16x8 af[4], bf[4];
#pragma unroll
            for (int mi = 0; mi < 4; ++mi) {
                int row = wm + mi * 16 + rl;
                af[mi] = *(const bf16x8*)&ldsA[row * 64 + (kg ^ (row & 7)) * 8];
            }
#pragma unroll
            for (int ni = 0; ni < 4; ++ni) {
                int row = wn + ni * 16 + rl;
                bf[ni] = *(const bf16x8*)&ldsB[row * 64 + (kg ^ (row & 7)) * 8];
            }
#pragma unroll
            for (int mi = 0; mi < 4; ++mi)
#pragma unroll
                for (int ni = 0; ni < 4; ++ni)
                    acc[mi][ni] = __builtin_amdgcn_mfma_f32_16x16x32_bf16(
                        af[mi], bf[ni], acc[mi][ni], 0, 0, 0);
        }
        __syncthreads();   // all reads done before next tile overwrites
    }
    // epilogue: C/D layout col = lane&15, row = quad*4 + reg
#pragma unroll
    for (int ni = 0; ni < 4; ++ni) {
        int col = n0 + wn + ni * 16 + rl;
        float bv = bias[col];
#pragma unroll
        for (int mi = 0; mi < 4; ++mi) {
            int rowb = m0 + wm + mi * 16 + quad * 4;
#pragma unroll
            for (int r = 0; r < 4; ++r) {
                float v = acc[mi][ni][r] + bv;
                if constexpr (MODE_H) v = v > 0.f ? v : 0.f;
                outp[(long)(rowb + r) * DDIM + col] = f2bf(v);
            }
        }
    }
}

// ---------------- combine: out = Xs + g0*OutE[s0] + g1*OutE[s1] ----------------
__global__ __launch_bounds__(256) void k_combine(
    const u16* __restrict__ Xs, const u16* __restrict__ OutE,
    const int* __restrict__ ts0, const int* __restrict__ ts1,
    const float* __restrict__ p0, const float* __restrict__ p1,
    float* __restrict__ out) {
    int b = blockIdx.x;
    int d = threadIdx.x * 4;
    long base = (long)b * DDIM + d;
    ushort4 xs4 = *(const ushort4*)(Xs + base);
    float r0 = bf2f(xs4.x), r1 = bf2f(xs4.y), r2 = bf2f(xs4.z), r3 = bf2f(xs4.w);
    int s0 = ts0[b], s1 = ts1[b];
    if (s0 >= 0) {
        float g = p0[b];
        ushort4 o4 = *(const ushort4*)(OutE + (long)s0 * DDIM + d);
        r0 += g * bf2f(o4.x); r1 += g * bf2f(o4.y); r2 += g * bf2f(o4.z); r3 += g * bf2f(o4.w);
    }
    if (s1 >= 0) {
        float g = p1[b];
        ushort4 o4 = *(const ushort4*)(OutE + (long)s1 * DDIM + d);
        r0 += g * bf2f(o4.x); r1 += g * bf2f(o4.y); r2 += g * bf2f(o4.z); r3 += g * bf2f(o4.w);
    }
    float4 w; w.x = r0; w.y = r1; w.z = r2; w.w = r3;
    *(float4*)(out + base) = w;
}

extern "C" void kernel_launch(void* const* d_in, const int* in_sizes, int n_in,
                              void* d_out, int out_size, void* d_ws, size_t ws_size,
                              hipStream_t stream) {
    const float* x    = (const float*)d_in[0];
    const float* noise= (const float*)d_in[1];
    const float* Wr   = (const float*)d_in[2];
    const float* br   = (const float*)d_in[3];
    const float* Wn   = (const float*)d_in[4];
    const float* bn   = (const float*)d_in[5];
    const float* W1   = (const float*)d_in[6];
    const float* b1   = (const float*)d_in[7];
    const float* W2   = (const float*)d_in[8];
    const float* b2   = (const float*)d_in[9];
    const float* Ws1  = (const float*)d_in[10];
    const float* bs1  = (const float*)d_in[11];
    const float* Ws2  = (const float*)d_in[12];
    const float* bs2  = (const float*)d_in[13];
    float* out = (float*)d_out;
    char* ws = (char*)d_ws;

    size_t off = 0;
    auto alloc = [&](size_t bytes) { size_t o = off; off += (bytes + 255) & ~(size_t)255; return o; };
    u16*  Wt   = (u16*)(ws + alloc(7ull * 1048576 * 2));
    u16*  Wst  = (u16*)(ws + alloc(1048576ull * 2));
    u16*  xb   = (u16*)(ws + alloc((size_t)NTOK * 1024 * 2));
    u16*  He   = (u16*)(ws + alloc((size_t)NEXP * CPAD * 1024 * 2));
    u16*  Hs   = (u16*)(ws + alloc((size_t)NTOK * 1024 * 2));
    u16*  OutE = (u16*)(ws + alloc((size_t)NEXP * CPAD * 1024 * 2));
    u16*  Xs   = (u16*)(ws + alloc((size_t)NTOK * 1024 * 2));
    int*  idx0 = (int*)(ws + alloc(NTOK * 4));
    int*  idx1 = (int*)(ws + alloc(NTOK * 4));
    float* p0  = (float*)(ws + alloc(NTOK * 4));
    float* p1  = (float*)(ws + alloc(NTOK * 4));
    int*  ts0  = (int*)(ws + alloc(NTOK * 4));
    int*  ts1  = (int*)(ws + alloc(NTOK * 4));
    int*  slot_token = (int*)(ws + alloc(NEXP * CPAD * 4));
    int*  cntA = (int*)(ws + alloc(7 * 128 * 4));
    int*  baseA= (int*)(ws + alloc(7 * 128 * 4));
    double* sumA = (double*)(ws + alloc(7 * 128 * 8));
    int*  cnt    = (int*)(ws + alloc(8 * 4));
    u16*  zrow   = (u16*)(ws + alloc(1024 * 2));
    double* arO  = (double*)(ws + alloc((size_t)NTOK * 7 * 8));
    double* anO  = (double*)(ws + alloc((size_t)NTOK * 7 * 8));
    size_t base_off = off;
    // optional separate phase-2 transpose buffers (removes mid-pipeline bubble)
    u16*  Wt2  = (u16*)(ws + alloc(7ull * 1048576 * 2));
    u16*  Wst2 = (u16*)(ws + alloc(1048576ull * 2));

    if (base_off > ws_size) {
        k_zero<<<2048, 256, 0, stream>>>(out, (long)out_size);
        return;
    }
    bool sep = (off <= ws_size);
    if (!sep) { Wt2 = Wt; Wst2 = Wst; }

    // fused: x->bf16 + inits + transpose set0 (+ set1 when sep)
    k_prep<<<sep ? 5120 : 4608, 256, 0, stream>>>(
        x, xb, slot_token, zrow, W1, Ws1, Wt, Wst, W2, Ws2, Wt2, Wst2);
    k_router<<<1024, 512, 0, stream>>>(x, Wr, Wn, arO, anO);
    k_tail<<<32, 256, 0, stream>>>(arO, anO, noise, br, bn, idx0, idx1, p0, p1, cntA, sumA);
    k_scanbase<<<1, 896, 0, stream>>>(cntA, sumA, baseA, cnt, out);
    k_assign<<<32, 256, 0, stream>>>(idx0, idx1, baseA, slot_token, ts0, ts1);

    // fused layer 1: experts (gather xb via slot_token) + shared, relu -> bf16 He/Hs
    k_gemm<true, true><<<TBLK, 256, 0, stream>>>(
        xb, xb, slot_token, zrow, Wt, Wst, b1, bs1, He, Hs, cnt);

    if (!sep)   // fallback: set1 transpose between the GEMMs
        k_transpose<<<512, 256, 0, stream>>>(W2, Ws2, Wt, Wst);

    // fused layer 2: -> bf16 OutE/Xs (+b2/bs2)
    k_gemm<false, false><<<TBLK, 256, 0, stream>>>(
        He, Hs, nullptr, zrow, Wt2, Wst2, b2, bs2, OutE, Xs, cnt);

    k_combine<<<NTOK, 256, 0, stream>>>(Xs, OutE, ts0, ts1, p0, p1, out);
    (void)in_sizes; (void)n_in; (void)out_size;
}

// Round 6
// 379.218 us; speedup vs baseline: 1.1476x; 1.0183x over previous
//
#include <hip/hip_runtime.h>
#include <math.h>

typedef unsigned short u16;
typedef __attribute__((ext_vector_type(4))) float f32x4;
typedef __bf16 bf16x8 __attribute__((ext_vector_type(8)));

#define NTOK 8192
#define DDIM 1024
#define NEXP 7
#define CAPC 2574      /* int(8192*2/7*1.1) */
#define CPAD 2688      /* 21*128 */
#define EBLK 1176      /* 7 experts * 21 mblk * 8 nblk */
#define TBLK 1688      /* + 64*8 shared blocks; 1688 = 8*211 exactly */
#define XCHK 211       /* blocks per XCD chunk */

__device__ inline float bf2f(u16 u) {
    union { unsigned int i; float f; } c; c.i = ((unsigned int)u) << 16; return c.f;
}
__device__ inline u16 f2bf(float f) {
    union { float f; unsigned int i; } c; c.f = f;
    unsigned int u = c.i;
    unsigned int r = (u + 0x7fffu + ((u >> 16) & 1u)) >> 16;
    return (u16)r;
}

__device__ inline void gl2lds16(const u16* g, const u16* l) {
    __builtin_amdgcn_global_load_lds(
        (const __attribute__((address_space(1))) unsigned int*)g,
        (__attribute__((address_space(3))) unsigned int*)l, 16, 0, 0);
}

// ---------------- guard: zero the output (ws_size-too-small diagnostic) ----------------
__global__ void k_zero(float* out, long n) {
    long i = (long)blockIdx.x * 256 + threadIdx.x;
    long stride = (long)gridDim.x * 256;
    for (; i < n; i += stride) out[i] = 0.f;
}

// ---------------- LDS-tiled transpose core: 256k x 64n tile, both sides coalesced ----------------
// dst[n*1024+k] = f2bf(src[k*1024+n]); LDS XOR swizzle s(n)=((n>>2)&7)<<3 breaks bank conflicts.
__device__ inline void tile_transpose(const float* __restrict__ src, u16* __restrict__ dst,
                                      int k0, int n0, int tid, u16 (*tbuf)[256]) {
#pragma unroll
    for (int p = 0; p < 16; ++p) {
        int kl = p * 16 + (tid >> 4);
        int nl = (tid & 15) * 4;
        float4 v = *(const float4*)(src + (long)(k0 + kl) * 1024 + n0 + nl);
        int s = (tid & 7) << 3;          /* ((nl>>2)&7)<<3 */
        int kx = kl ^ s;
        tbuf[nl + 0][kx] = f2bf(v.x);
        tbuf[nl + 1][kx] = f2bf(v.y);
        tbuf[nl + 2][kx] = f2bf(v.z);
        tbuf[nl + 3][kx] = f2bf(v.w);
    }
    __syncthreads();
#pragma unroll
    for (int q = 0; q < 8; ++q) {
        int nl = q * 8 + (tid >> 5);
        int kl = (tid & 31) * 8;
        int s = ((nl >> 2) & 7) << 3;
        const u16* pr = &tbuf[nl][kl ^ s];
        ushort4 a = *(const ushort4*)pr;
        ushort4 b = *(const ushort4*)(pr + 4);
        u16* pd = dst + (long)(n0 + nl) * 1024 + k0 + kl;
        *(ushort4*)pd = a;
        *(ushort4*)(pd + 4) = b;
    }
}

// ---------------- fused prep ----------------
// blocks 0..4095: x->bf16 + inits; 4096+: LDS-tiled transposes.
// set0 = {W1(7), Ws1} (blocks 4096..4607); set1 = {W2(7), Ws2} (4608..5119, only when sep).
__global__ void k_prep(const float* __restrict__ x, u16* __restrict__ xb,
                       int* __restrict__ slot_token, u16* __restrict__ zrow,
                       const float* __restrict__ W1, const float* __restrict__ Ws1,
                       u16* __restrict__ Wt, u16* __restrict__ Wst,
                       const float* __restrict__ W2, const float* __restrict__ Ws2,
                       u16* __restrict__ Wt2, u16* __restrict__ Wst2) {
    __shared__ u16 tbuf[64][256];
    int bid = blockIdx.x, tid = threadIdx.x;
    if (bid < 4096) {
        int gid = bid * 256 + tid;
        int i = gid * 8;
        float4 a = *(const float4*)(x + i);
        float4 b = *(const float4*)(x + i + 4);
        ushort4 o0; o0.x = f2bf(a.x); o0.y = f2bf(a.y); o0.z = f2bf(a.z); o0.w = f2bf(a.w);
        ushort4 o1; o1.x = f2bf(b.x); o1.y = f2bf(b.y); o1.z = f2bf(b.z); o1.w = f2bf(b.w);
        *(ushort4*)(xb + i) = o0;
        *(ushort4*)(xb + i + 4) = o1;
        if (gid < DDIM) zrow[gid] = 0;
        if (gid < NEXP * CPAD) slot_token[gid] = NTOK;
        return;
    }
    int tb = bid - 4096;
    int set = tb >> 9;          /* 0 or 1 */
    int t9 = tb & 511;
    int z = t9 >> 6;            /* matrix 0..7 */
    int rem = t9 & 63;
    int k0 = (rem >> 4) * 256;
    int n0 = (rem & 15) * 64;
    const float* srcE = set ? W2 : W1;
    const float* srcS = set ? Ws2 : Ws1;
    u16* dE = set ? Wt2 : Wt;
    u16* dS = set ? Wst2 : Wst;
    const float* src; u16* dst;
    if (z < 7) { src = srcE + (long)z * 1048576; dst = dE + (long)z * 1048576; }
    else       { src = srcS;                     dst = dS; }
    tile_transpose(src, dst, k0, n0, tid, tbuf);
}

// ---------------- weight transpose phase 2 (fallback when !sep): set1 only ----------------
__global__ void k_transpose(const float* __restrict__ srcE, const float* __restrict__ srcS,
                            u16* __restrict__ Wt, u16* __restrict__ Wst) {
    __shared__ u16 tbuf[64][256];
    int bid = blockIdx.x, tid = threadIdx.x;
    int z = bid >> 6;
    int rem = bid & 63;
    int k0 = (rem >> 4) * 256;
    int n0 = (rem & 15) * 64;
    const float* src; u16* dst;
    if (z < 7) { src = srcE + (long)z * 1048576; dst = Wt + (long)z * 1048576; }
    else       { src = srcS;                     dst = Wst; }
    tile_transpose(src, dst, k0, n0, tid, tbuf);
}

// ---------------- router main: fp64 dot-products only (no libm -> low VGPR) ----------------
__global__ __launch_bounds__(512) void k_router(
    const float* __restrict__ x,
    const float* __restrict__ Wr, const float* __restrict__ Wn,
    double* __restrict__ arO, double* __restrict__ anO) {
    __shared__ float swr[7168];
    __shared__ float swn[7168];
    int tid = threadIdx.x;
    for (int i = tid; i < 7168; i += 512) { swr[i] = Wr[i]; swn[i] = Wn[i]; }
    __syncthreads();
    int lane = tid & 63, wv = tid >> 6;
    int t = blockIdx.x * 8 + wv;
    double ar[7] = {0,0,0,0,0,0,0}, an[7] = {0,0,0,0,0,0,0};
    for (int j = 0; j < 16; ++j) {
        int d = j * 64 + lane;
        double xd = (double)x[t * 1024 + d];
#pragma unroll
        for (int e = 0; e < 7; ++e) {
            ar[e] += xd * (double)swr[d * 7 + e];
            an[e] += xd * (double)swn[d * 7 + e];
        }
    }
#pragma unroll
    for (int e = 0; e < 7; ++e) {
        for (int o = 32; o > 0; o >>= 1) {
            ar[e] += __shfl_xor(ar[e], o);
            an[e] += __shfl_xor(an[e], o);
        }
    }
    if (lane == 0) {
#pragma unroll
        for (int e = 0; e < 7; ++e) { arO[t * 7 + e] = ar[e]; anO[t * 7 + e] = an[e]; }
    }
}

// ---------------- router tail + count ----------------
__global__ void k_tail(const double* __restrict__ arO, const double* __restrict__ anO,
                       const float* __restrict__ noise,
                       const float* __restrict__ br, const float* __restrict__ bn,
                       int* __restrict__ idx0, int* __restrict__ idx1,
                       float* __restrict__ p0, float* __restrict__ p1,
                       int* __restrict__ cntA, double* __restrict__ sumA) {
    int t = blockIdx.x * 256 + threadIdx.x;
    int lane = threadIdx.x & 63;
    double best = -1e300, second = -1e300; int b0 = 0, b1 = 0;
#pragma unroll
    for (int e = 0; e < 7; ++e) {
        double lg = arO[t * 7 + e] + (double)br[e];
        double z  = anO[t * 7 + e] + (double)bn[e];
        double sp = (z > 30.0) ? (z + log1p(exp(-z))) : log1p(exp(z));
        double v  = lg + (double)noise[t * 7 + e] * sp;
        if (v > best)        { second = best; b1 = b0; best = v; b0 = e; }
        else if (v > second) { second = v; b1 = e; }
    }
    double ex = exp(second - best);
    float q0 = (float)(1.0 / (1.0 + ex));
    float q1 = (float)(ex / (1.0 + ex));
    idx0[t] = b0; idx1[t] = b1; p0[t] = q0; p1[t] = q1;
    int chunk = t >> 6;
    double dq0 = (double)q0, dq1 = (double)q1;
#pragma unroll
    for (int e = 0; e < 7; ++e) {
        unsigned long long m = __ballot((b0 == e) || (b1 == e));
        double q = (b0 == e ? dq0 : 0.0) + (b1 == e ? dq1 : 0.0);
        for (int o = 32; o > 0; o >>= 1) q += __shfl_xor(q, o);
        if (lane == 0) { cntA[e * 128 + chunk] = __popcll(m); sumA[e * 128 + chunk] = q; }
    }
}

// ---------------- phase B: exclusive scan (7 experts in parallel) + lbl ----------------
__global__ void k_scanbase(const int* __restrict__ cntA, const double* __restrict__ sumA,
                           int* __restrict__ baseA, int* __restrict__ cnt,
                           float* __restrict__ out) {
    __shared__ int s[7][128];
    __shared__ double rd[7][128];
    __shared__ int rawc[7];
    __shared__ double ps[7];
    int tid = threadIdx.x;            /* 896 threads: e = tid>>7, i = tid&127 */
    int e = tid >> 7, i = tid & 127;
    int v = cntA[e * 128 + i];
    s[e][i] = v;
    rd[e][i] = sumA[e * 128 + i];
    __syncthreads();
    for (int o = 1; o < 128; o <<= 1) {
        int add = (i >= o) ? s[e][i - o] : 0;
        __syncthreads();
        s[e][i] += add;
        __syncthreads();
    }
    baseA[e * 128 + i] = s[e][i] - v;
    if (i == 127) { rawc[e] = s[e][127]; cnt[e] = (s[e][127] < CAPC) ? s[e][127] : CAPC; }
    for (int o = 64; o > 0; o >>= 1) {
        if (i < o) rd[e][i] += rd[e][i + o];
        __syncthreads();
    }
    if (i == 0) ps[e] = rd[e][0];
    __syncthreads();
    if (tid == 0) {
        double acc = 0.0;
        for (int ee = 0; ee < 7; ++ee) acc += ps[ee] * (double)rawc[ee];
        out[(long)NTOK * DDIM] = (float)(7.0 * acc / (8192.0 * 8192.0));
    }
}

// ---------------- phase C: slot assignment (FCFS, capacity-dropped) ----------------
__global__ void k_assign(const int* __restrict__ idx0, const int* __restrict__ idx1,
                         const int* __restrict__ baseA, int* __restrict__ slot_token,
                         int* __restrict__ ts0, int* __restrict__ ts1) {
    int lane = threadIdx.x & 63;
    int chunk = (blockIdx.x * 256 + threadIdx.x) >> 6;
    int t = chunk * 64 + lane;
    int i0 = idx0[t], i1 = idx1[t];
    int myts0 = -1, myts1 = -1;
    unsigned long long lt = (1ull << lane) - 1ull;
#pragma unroll
    for (int e = 0; e < 7; ++e) {
        bool has = (i0 == e) || (i1 == e);
        unsigned long long m = __ballot(has);
        int pre = __popcll(m & lt);
        int pos = baseA[e * 128 + chunk] + pre;
        if (has && pos < CAPC) {
            int slot = e * CPAD + pos;
            slot_token[slot] = t;
            if (i0 == e) myts0 = slot; else myts1 = slot;
        }
    }
    ts0[t] = myts0; ts1[t] = myts1;
}

// ---------------- fused MFMA GEMM (round-0 structure + T1 XCD-chunked swizzle) ----------------
// 128x128 tile, BK=64, global_load_lds width-16 staging, 32 KiB LDS -> 3+ blocks/CU.
// Cross-block co-residency hides the staging drain; do NOT add dbuf (r4: -25%).
// T1: phys%8 = XCD (round-robin dispatch) -> give each XCD a CONTIGUOUS run of 211
// logical blocks so A-panels (8 consecutive lids) and B-panels (period 8) hit the
// same XCD's L2 instead of being re-fetched into 8 non-coherent L2s (r5: 211 MB
// FETCH vs ~70 MB unique).
template <bool GATHER, bool MODE_H>
__global__ __launch_bounds__(256) void k_gemm(
    const u16* __restrict__ AbaseE, const u16* __restrict__ AbaseS,
    const int* __restrict__ gidx, const u16* __restrict__ zrow,
    const u16* __restrict__ WtE, const u16* __restrict__ WtS,
    const float* __restrict__ biasE, const float* __restrict__ biasS,
    u16* __restrict__ outE, u16* __restrict__ outS,
    const int* __restrict__ cnt) {
    __shared__ __align__(16) u16 ldsA[128 * 64];
    __shared__ __align__(16) u16 ldsB[128 * 64];
    int phys = blockIdx.x;
    int bid = (phys & 7) * XCHK + (phys >> 3);   // bijective: TBLK == 8*XCHK
    int tid = threadIdx.x, lane = tid & 63, wv = tid >> 6;
    int lrow = lane >> 3, lkg = lane & 7;
    int kgs = lkg ^ lrow;

    int e = 0, my, nx;
    const u16* Ab; const u16* Bb; const float* bias; u16* outp;
    bool gather = false;
    if (bid < EBLK) {
        e = bid / 168; int r = bid % 168; my = r >> 3; nx = r & 7;
        if (my * 128 >= cnt[e]) return;
        Ab = AbaseE + (GATHER ? 0L : (long)e * CPAD * 1024);
        Bb = WtE + ((long)e << 20);
        bias = biasE + e * 1024;
        outp = outE + (long)e * CPAD * 1024;
        gather = GATHER;
    } else {
        int sb = bid - EBLK; my = sb >> 3; nx = sb & 7;
        Ab = AbaseS; Bb = WtS; bias = biasS; outp = outS;
    }
    int m0 = my * 128, n0 = nx * 128;

    const u16* arow[4];
    const u16* brow[4];
#pragma unroll
    for (int i = 0; i < 4; ++i) {
        int r = (wv * 4 + i) * 8 + lrow;     // 0..127
        if (gather) {
            int tok = gidx[e * CPAD + m0 + r];
            arow[i] = (tok < NTOK) ? (AbaseE + (long)tok * DDIM) : zrow;
        } else {
            arow[i] = Ab + (long)(m0 + r) * DDIM;
        }
        brow[i] = Bb + (long)(n0 + r) * DDIM;
    }
    f32x4 acc[4][4];
#pragma unroll
    for (int a = 0; a < 4; ++a)
#pragma unroll
        for (int b = 0; b < 4; ++b) { f32x4 z = {0.f, 0.f, 0.f, 0.f}; acc[a][b] = z; }

    int wm = (wv >> 1) * 64, wn = (wv & 1) * 64;
    int rl = lane & 15, quad = lane >> 4;

    for (int k0 = 0; k0 < 1024; k0 += 64) {
#pragma unroll
        for (int i = 0; i < 4; ++i) {
            gl2lds16(arow[i] + k0 + kgs * 8, &ldsA[(wv * 4 + i) * 512]);
            gl2lds16(brow[i] + k0 + kgs * 8, &ldsB[(wv * 4 + i) * 512]);
        }
        __syncthreads();   // drains vmcnt -> staged tile visible
#pragma unroll
        for (int ks = 0; ks < 2; ++ks) {
            int kg = ks * 4 + quad;
            bf16x8 af[4], bf[4];
#pragma unroll
            for (int mi = 0; mi < 4; ++mi) {
                int row = wm + mi * 16 + rl;
                af[mi] = *(const bf16x8*)&ldsA[row * 64 + (kg ^ (row & 7)) * 8];
            }
#pragma unroll
            for (int ni = 0; ni < 4; ++ni) {
                int row = wn + ni * 16 + rl;
                bf[ni] = *(const bf16x8*)&ldsB[row * 64 + (kg ^ (row & 7)) * 8];
            }
#pragma unroll
            for (int mi = 0; mi < 4; ++mi)
#pragma unroll
                for (int ni = 0; ni < 4; ++ni)
                    acc[mi][ni] = __builtin_amdgcn_mfma_f32_16x16x32_bf16(
                        af[mi], bf[ni], acc[mi][ni], 0, 0, 0);
        }
        __syncthreads();   // all reads done before next tile overwrites
    }
    // epilogue: C/D layout col = lane&15, row = quad*4 + reg
#pragma unroll
    for (int ni = 0; ni < 4; ++ni) {
        int col = n0 + wn + ni * 16 + rl;
        float bv = bias[col];
#pragma unroll
        for (int mi = 0; mi < 4; ++mi) {
            int rowb = m0 + wm + mi * 16 + quad * 4;
#pragma unroll
            for (int r = 0; r < 4; ++r) {
                float v = acc[mi][ni][r] + bv;
                if constexpr (MODE_H) v = v > 0.f ? v : 0.f;
                outp[(long)(rowb + r) * DDIM + col] = f2bf(v);
            }
        }
    }
}

// ---------------- combine: out = Xs + g0*OutE[s0] + g1*OutE[s1] ----------------
__global__ __launch_bounds__(256) void k_combine(
    const u16* __restrict__ Xs, const u16* __restrict__ OutE,
    const int* __restrict__ ts0, const int* __restrict__ ts1,
    const float* __restrict__ p0, const float* __restrict__ p1,
    float* __restrict__ out) {
    int b = blockIdx.x;
    int d = threadIdx.x * 4;
    long base = (long)b * DDIM + d;
    ushort4 xs4 = *(const ushort4*)(Xs + base);
    float r0 = bf2f(xs4.x), r1 = bf2f(xs4.y), r2 = bf2f(xs4.z), r3 = bf2f(xs4.w);
    int s0 = ts0[b], s1 = ts1[b];
    if (s0 >= 0) {
        float g = p0[b];
        ushort4 o4 = *(const ushort4*)(OutE + (long)s0 * DDIM + d);
        r0 += g * bf2f(o4.x); r1 += g * bf2f(o4.y); r2 += g * bf2f(o4.z); r3 += g * bf2f(o4.w);
    }
    if (s1 >= 0) {
        float g = p1[b];
        ushort4 o4 = *(const ushort4*)(OutE + (long)s1 * DDIM + d);
        r0 += g * bf2f(o4.x); r1 += g * bf2f(o4.y); r2 += g * bf2f(o4.z); r3 += g * bf2f(o4.w);
    }
    float4 w; w.x = r0; w.y = r1; w.z = r2; w.w = r3;
    *(float4*)(out + base) = w;
}

extern "C" void kernel_launch(void* const* d_in, const int* in_sizes, int n_in,
                              void* d_out, int out_size, void* d_ws, size_t ws_size,
                              hipStream_t stream) {
    const float* x    = (const float*)d_in[0];
    const float* noise= (const float*)d_in[1];
    const float* Wr   = (const float*)d_in[2];
    const float* br   = (const float*)d_in[3];
    const float* Wn   = (const float*)d_in[4];
    const float* bn   = (const float*)d_in[5];
    const float* W1   = (const float*)d_in[6];
    const float* b1   = (const float*)d_in[7];
    const float* W2   = (const float*)d_in[8];
    const float* b2   = (const float*)d_in[9];
    const float* Ws1  = (const float*)d_in[10];
    const float* bs1  = (const float*)d_in[11];
    const float* Ws2  = (const float*)d_in[12];
    const float* bs2  = (const float*)d_in[13];
    float* out = (float*)d_out;
    char* ws = (char*)d_ws;

    size_t off = 0;
    auto alloc = [&](size_t bytes) { size_t o = off; off += (bytes + 255) & ~(size_t)255; return o; };
    u16*  Wt   = (u16*)(ws + alloc(7ull * 1048576 * 2));
    u16*  Wst  = (u16*)(ws + alloc(1048576ull * 2));
    u16*  xb   = (u16*)(ws + alloc((size_t)NTOK * 1024 * 2));
    u16*  He   = (u16*)(ws + alloc((size_t)NEXP * CPAD * 1024 * 2));
    u16*  Hs   = (u16*)(ws + alloc((size_t)NTOK * 1024 * 2));
    u16*  OutE = (u16*)(ws + alloc((size_t)NEXP * CPAD * 1024 * 2));
    u16*  Xs   = (u16*)(ws + alloc((size_t)NTOK * 1024 * 2));
    int*  idx0 = (int*)(ws + alloc(NTOK * 4));
    int*  idx1 = (int*)(ws + alloc(NTOK * 4));
    float* p0  = (float*)(ws + alloc(NTOK * 4));
    float* p1  = (float*)(ws + alloc(NTOK * 4));
    int*  ts0  = (int*)(ws + alloc(NTOK * 4));
    int*  ts1  = (int*)(ws + alloc(NTOK * 4));
    int*  slot_token = (int*)(ws + alloc(NEXP * CPAD * 4));
    int*  cntA = (int*)(ws + alloc(7 * 128 * 4));
    int*  baseA= (int*)(ws + alloc(7 * 128 * 4));
    double* sumA = (double*)(ws + alloc(7 * 128 * 8));
    int*  cnt    = (int*)(ws + alloc(8 * 4));
    u16*  zrow   = (u16*)(ws + alloc(1024 * 2));
    double* arO  = (double*)(ws + alloc((size_t)NTOK * 7 * 8));
    double* anO  = (double*)(ws + alloc((size_t)NTOK * 7 * 8));
    size_t base_off = off;
    // optional separate phase-2 transpose buffers (removes mid-pipeline bubble)
    u16*  Wt2  = (u16*)(ws + alloc(7ull * 1048576 * 2));
    u16*  Wst2 = (u16*)(ws + alloc(1048576ull * 2));

    if (base_off > ws_size) {
        k_zero<<<2048, 256, 0, stream>>>(out, (long)out_size);
        return;
    }
    bool sep = (off <= ws_size);
    if (!sep) { Wt2 = Wt; Wst2 = Wst; }

    // fused: x->bf16 + inits + transpose set0 (+ set1 when sep)
    k_prep<<<sep ? 5120 : 4608, 256, 0, stream>>>(
        x, xb, slot_token, zrow, W1, Ws1, Wt, Wst, W2, Ws2, Wt2, Wst2);
    k_router<<<1024, 512, 0, stream>>>(x, Wr, Wn, arO, anO);
    k_tail<<<32, 256, 0, stream>>>(arO, anO, noise, br, bn, idx0, idx1, p0, p1, cntA, sumA);
    k_scanbase<<<1, 896, 0, stream>>>(cntA, sumA, baseA, cnt, out);
    k_assign<<<32, 256, 0, stream>>>(idx0, idx1, baseA, slot_token, ts0, ts1);

    // fused layer 1: experts (gather xb via slot_token) + shared, relu -> bf16 He/Hs
    k_gemm<true, true><<<TBLK, 256, 0, stream>>>(
        xb, xb, slot_token, zrow, Wt, Wst, b1, bs1, He, Hs, cnt);

    if (!sep)   // fallback: set1 transpose between the GEMMs
        k_transpose<<<512, 256, 0, stream>>>(W2, Ws2, Wt, Wst);

    // fused layer 2: -> bf16 OutE/Xs (+b2/bs2)
    k_gemm<false, false><<<TBLK, 256, 0, stream>>>(
        He, Hs, nullptr, zrow, Wt2, Wst2, b2, bs2, OutE, Xs, cnt);

    k_combine<<<NTOK, 256, 0, stream>>>(Xs, OutE, ts0, ts1, p0, p1, out);
    (void)in_sizes; (void)n_in; (void)out_size;
}

// Round 7
// 371.518 us; speedup vs baseline: 1.1714x; 1.0207x over previous
//
#include <hip/hip_runtime.h>
#include <math.h>

typedef unsigned short u16;
typedef __attribute__((ext_vector_type(4))) float f32x4;
typedef __bf16 bf16x8 __attribute__((ext_vector_type(8)));

#define NTOK 8192
#define DDIM 1024
#define NEXP 7
#define CAPC 2574      /* int(8192*2/7*1.1) */
#define CPAD 2688      /* 21*128 */
#define EBLK 1176      /* 7 experts * 21 mblk * 8 nblk */
#define TBLK 1688      /* + 64*8 shared blocks; 1688 = 8*211 exactly */
#define XCHK 211       /* blocks per XCD chunk */

__device__ inline float bf2f(u16 u) {
    union { unsigned int i; float f; } c; c.i = ((unsigned int)u) << 16; return c.f;
}
__device__ inline u16 f2bf(float f) {
    union { float f; unsigned int i; } c; c.f = f;
    unsigned int u = c.i;
    unsigned int r = (u + 0x7fffu + ((u >> 16) & 1u)) >> 16;
    return (u16)r;
}

__device__ inline void gl2lds16(const u16* g, const u16* l) {
    __builtin_amdgcn_global_load_lds(
        (const __attribute__((address_space(1))) unsigned int*)g,
        (__attribute__((address_space(3))) unsigned int*)l, 16, 0, 0);
}

// ---------------- guard: zero the output (ws_size-too-small diagnostic) ----------------
__global__ void k_zero(float* out, long n) {
    long i = (long)blockIdx.x * 256 + threadIdx.x;
    long stride = (long)gridDim.x * 256;
    for (; i < n; i += stride) out[i] = 0.f;
}

// ---------------- LDS-tiled transpose core: 256k x 64n tile, both sides coalesced ----------------
__device__ inline void tile_transpose(const float* __restrict__ src, u16* __restrict__ dst,
                                      int k0, int n0, int tid, u16 (*tbuf)[256]) {
#pragma unroll
    for (int p = 0; p < 16; ++p) {
        int kl = p * 16 + (tid >> 4);
        int nl = (tid & 15) * 4;
        float4 v = *(const float4*)(src + (long)(k0 + kl) * 1024 + n0 + nl);
        int s = (tid & 7) << 3;          /* ((nl>>2)&7)<<3 */
        int kx = kl ^ s;
        tbuf[nl + 0][kx] = f2bf(v.x);
        tbuf[nl + 1][kx] = f2bf(v.y);
        tbuf[nl + 2][kx] = f2bf(v.z);
        tbuf[nl + 3][kx] = f2bf(v.w);
    }
    __syncthreads();
#pragma unroll
    for (int q = 0; q < 8; ++q) {
        int nl = q * 8 + (tid >> 5);
        int kl = (tid & 31) * 8;
        int s = ((nl >> 2) & 7) << 3;
        const u16* pr = &tbuf[nl][kl ^ s];
        ushort4 a = *(const ushort4*)pr;
        ushort4 b = *(const ushort4*)(pr + 4);
        u16* pd = dst + (long)(n0 + nl) * 1024 + k0 + kl;
        *(ushort4*)pd = a;
        *(ushort4*)(pd + 4) = b;
    }
}

// ---------------- prep: weight transposes + inits (x-conversion moved into k_router) ----------------
// blocks 0..ntb-1: transposes (set0 = W1/Ws1; set1 = W2/Ws2 when sep); blocks ntb..ntb+73: inits.
__global__ void k_prep(int* __restrict__ slot_token, u16* __restrict__ zrow,
                       const float* __restrict__ W1, const float* __restrict__ Ws1,
                       u16* __restrict__ Wt, u16* __restrict__ Wst,
                       const float* __restrict__ W2, const float* __restrict__ Ws2,
                       u16* __restrict__ Wt2, u16* __restrict__ Wst2, int ntb) {
    __shared__ u16 tbuf[64][256];
    int bid = blockIdx.x, tid = threadIdx.x;
    if (bid >= ntb) {
        int gid = (bid - ntb) * 256 + tid;
        if (gid < NEXP * CPAD) slot_token[gid] = NTOK;
        if (gid < DDIM) zrow[gid] = 0;
        return;
    }
    int set = bid >> 9;          /* 0 or 1 (ntb=512 when !sep -> always 0) */
    int t9 = bid & 511;
    int z = t9 >> 6;             /* matrix 0..7 */
    int rem = t9 & 63;
    int k0 = (rem >> 4) * 256;
    int n0 = (rem & 15) * 64;
    const float* srcE = set ? W2 : W1;
    const float* srcS = set ? Ws2 : Ws1;
    u16* dE = set ? Wt2 : Wt;
    u16* dS = set ? Wst2 : Wst;
    const float* src; u16* dst;
    if (z < 7) { src = srcE + (long)z * 1048576; dst = dE + (long)z * 1048576; }
    else       { src = srcS;                     dst = dS; }
    tile_transpose(src, dst, k0, n0, tid, tbuf);
}

// ---------------- weight transpose phase 2 (fallback when !sep): set1 only ----------------
__global__ void k_transpose(const float* __restrict__ srcE, const float* __restrict__ srcS,
                            u16* __restrict__ Wt, u16* __restrict__ Wst) {
    __shared__ u16 tbuf[64][256];
    int bid = blockIdx.x, tid = threadIdx.x;
    int z = bid >> 6;
    int rem = bid & 63;
    int k0 = (rem >> 4) * 256;
    int n0 = (rem & 15) * 64;
    const float* src; u16* dst;
    if (z < 7) { src = srcE + (long)z * 1048576; dst = Wt + (long)z * 1048576; }
    else       { src = srcS;                     dst = Wst; }
    tile_transpose(src, dst, k0, n0, tid, tbuf);
}

// ---------------- fused router: logits (fp64) + x->bf16 + tail (top-2/softmax) + chunk-8 counts ----------------
// 1024 blocks x 512 thr; wave wv owns token t = bid*8+wv; block = one 8-token chunk.
__global__ __launch_bounds__(512) void k_router(
    const float* __restrict__ x,
    const float* __restrict__ Wr, const float* __restrict__ Wn,
    const float* __restrict__ br, const float* __restrict__ bn,
    const float* __restrict__ noise,
    u16* __restrict__ xb,
    int* __restrict__ idx0, int* __restrict__ idx1,
    float* __restrict__ p0, float* __restrict__ p1,
    int* __restrict__ cnt8, double* __restrict__ sum8) {
    __shared__ float swr[7][1024];
    __shared__ float swn[7][1024];
    __shared__ int sb0[8], sb1[8];
    __shared__ double sq0[8], sq1[8];
    int tid = threadIdx.x;
    for (int i = tid; i < 7168; i += 512) {
        int d = i / 7, e = i - d * 7;
        float vr = Wr[i], vn = Wn[i];
        swr[e][d] = vr; swn[e][d] = vn;
    }
    __syncthreads();
    int lane = tid & 63, wv = tid >> 6;
    int t = blockIdx.x * 8 + wv;
    double ar[7] = {0,0,0,0,0,0,0}, an[7] = {0,0,0,0,0,0,0};
#pragma unroll
    for (int j = 0; j < 4; ++j) {
        int d0 = j * 256 + lane * 4;
        float4 xv = *(const float4*)(x + (long)t * 1024 + d0);
        ushort4 o; o.x = f2bf(xv.x); o.y = f2bf(xv.y); o.z = f2bf(xv.z); o.w = f2bf(xv.w);
        *(ushort4*)(xb + (long)t * 1024 + d0) = o;
#pragma unroll
        for (int e = 0; e < 7; ++e) {
            float4 w4 = *(const float4*)&swr[e][d0];
            float4 n4 = *(const float4*)&swn[e][d0];
            ar[e] += (double)xv.x * (double)w4.x; an[e] += (double)xv.x * (double)n4.x;
            ar[e] += (double)xv.y * (double)w4.y; an[e] += (double)xv.y * (double)n4.y;
            ar[e] += (double)xv.z * (double)w4.z; an[e] += (double)xv.z * (double)n4.z;
            ar[e] += (double)xv.w * (double)w4.w; an[e] += (double)xv.w * (double)n4.w;
        }
    }
#pragma unroll
    for (int e = 0; e < 7; ++e) {
        for (int o = 32; o > 0; o >>= 1) {
            ar[e] += __shfl_xor(ar[e], o);
            an[e] += __shfl_xor(an[e], o);
        }
    }
    if (lane == 0) {
        double best = -1e300, second = -1e300; int b0 = 0, b1 = 0;
#pragma unroll
        for (int e = 0; e < 7; ++e) {
            double lg = ar[e] + (double)br[e];
            double z  = an[e] + (double)bn[e];
            double sp = (z > 30.0) ? (z + log1p(exp(-z))) : log1p(exp(z));
            double v  = lg + (double)noise[t * 7 + e] * sp;
            if (v > best)        { second = best; b1 = b0; best = v; b0 = e; }
            else if (v > second) { second = v; b1 = e; }
        }
        double ex = exp(second - best);
        double q0 = 1.0 / (1.0 + ex);
        double q1 = ex / (1.0 + ex);
        idx0[t] = b0; idx1[t] = b1; p0[t] = (float)q0; p1[t] = (float)q1;
        sb0[wv] = b0; sb1[wv] = b1; sq0[wv] = q0; sq1[wv] = q1;
    }
    __syncthreads();
    if (tid < 7) {
        int c = 0; double s = 0.0;
#pragma unroll
        for (int w = 0; w < 8; ++w) {
            if (sb0[w] == tid) { c++; s += sq0[w]; }
            if (sb1[w] == tid) { c++; s += sq1[w]; }
        }
        cnt8[tid * 1024 + blockIdx.x] = c;
        sum8[tid * 1024 + blockIdx.x] = s;
    }
}

// ---------------- phase B: scan of chunk-8 counts (7 experts parallel) + base8 + lbl ----------------
__global__ void k_scanbase(const int* __restrict__ cnt8, const double* __restrict__ sum8,
                           int* __restrict__ base8, int* __restrict__ cnt,
                           float* __restrict__ out) {
    __shared__ int s[7][128];
    __shared__ double rd[7][128];
    __shared__ int rawc[7];
    __shared__ double ps[7];
    int tid = threadIdx.x;            /* 896 threads: e = tid>>7, i = tid&127 (chunk64) */
    int e = tid >> 7, i = tid & 127;
    int c8[8]; int v = 0; double s64 = 0.0;
#pragma unroll
    for (int j = 0; j < 8; ++j) {
        c8[j] = cnt8[e * 1024 + i * 8 + j];
        v += c8[j];
        s64 += sum8[e * 1024 + i * 8 + j];
    }
    s[e][i] = v;
    rd[e][i] = s64;
    __syncthreads();
    for (int o = 1; o < 128; o <<= 1) {
        int add = (i >= o) ? s[e][i - o] : 0;
        __syncthreads();
        s[e][i] += add;
        __syncthreads();
    }
    int run = s[e][i] - v;            /* exclusive base of this chunk64 */
#pragma unroll
    for (int j = 0; j < 8; ++j) { base8[e * 1024 + i * 8 + j] = run; run += c8[j]; }
    if (i == 127) { rawc[e] = s[e][127]; cnt[e] = (s[e][127] < CAPC) ? s[e][127] : CAPC; }
    for (int o = 64; o > 0; o >>= 1) {
        if (i < o) rd[e][i] += rd[e][i + o];
        __syncthreads();
    }
    if (i == 0) ps[e] = rd[e][0];
    __syncthreads();
    if (tid == 0) {
        double acc = 0.0;
        for (int ee = 0; ee < 7; ++ee) acc += ps[ee] * (double)rawc[ee];
        out[(long)NTOK * DDIM] = (float)(7.0 * acc / (8192.0 * 8192.0));
    }
}

// ---------------- phase C: slot assignment (FCFS, capacity-dropped), chunk-8 ballots ----------------
__global__ void k_assign(const int* __restrict__ idx0, const int* __restrict__ idx1,
                         const int* __restrict__ base8, int* __restrict__ slot_token,
                         int* __restrict__ ts0, int* __restrict__ ts1) {
    int t = blockIdx.x * 256 + threadIdx.x;
    int lane = threadIdx.x & 63;
    int i0 = idx0[t], i1 = idx1[t];
    int myts0 = -1, myts1 = -1;
    unsigned long long gm = 0xFFull << ((lane >> 3) * 8);
    unsigned long long lt = (1ull << lane) - 1ull;
    int chunk = t >> 3;
#pragma unroll
    for (int e = 0; e < 7; ++e) {
        bool has = (i0 == e) || (i1 == e);
        unsigned long long m = __ballot(has);
        int pre = __popcll(m & lt & gm);
        int pos = base8[e * 1024 + chunk] + pre;
        if (has && pos < CAPC) {
            int slot = e * CPAD + pos;
            slot_token[slot] = t;
            if (i0 == e) myts0 = slot; else myts1 = slot;
        }
    }
    ts0[t] = myts0; ts1[t] = myts1;
}

// ---------------- fused MFMA GEMM (round-0 structure + T1 XCD-chunked swizzle) ----------------
// 128x128 tile, BK=64, global_load_lds width-16 staging, 32 KiB LDS -> 3+ blocks/CU.
// Cross-block co-residency hides the staging drain; do NOT add dbuf (r4: -25%).
// T1 swizzle verified r6: FETCH 211->61 MB; GEMM now latency/structure-bound (closed).
template <bool GATHER, bool MODE_H>
__global__ __launch_bounds__(256) void k_gemm(
    const u16* __restrict__ AbaseE, const u16* __restrict__ AbaseS,
    const int* __restrict__ gidx, const u16* __restrict__ zrow,
    const u16* __restrict__ WtE, const u16* __restrict__ WtS,
    const float* __restrict__ biasE, const float* __restrict__ biasS,
    u16* __restrict__ outE, u16* __restrict__ outS,
    const int* __restrict__ cnt) {
    __shared__ __align__(16) u16 ldsA[128 * 64];
    __shared__ __align__(16) u16 ldsB[128 * 64];
    int phys = blockIdx.x;
    int bid = (phys & 7) * XCHK + (phys >> 3);   // bijective: TBLK == 8*XCHK
    int tid = threadIdx.x, lane = tid & 63, wv = tid >> 6;
    int lrow = lane >> 3, lkg = lane & 7;
    int kgs = lkg ^ lrow;

    int e = 0, my, nx;
    const u16* Ab; const u16* Bb; const float* bias; u16* outp;
    bool gather = false;
    if (bid < EBLK) {
        e = bid / 168; int r = bid % 168; my = r >> 3; nx = r & 7;
        if (my * 128 >= cnt[e]) return;
        Ab = AbaseE + (GATHER ? 0L : (long)e * CPAD * 1024);
        Bb = WtE + ((long)e << 20);
        bias = biasE + e * 1024;
        outp = outE + (long)e * CPAD * 1024;
        gather = GATHER;
    } else {
        int sb = bid - EBLK; my = sb >> 3; nx = sb & 7;
        Ab = AbaseS; Bb = WtS; bias = biasS; outp = outS;
    }
    int m0 = my * 128, n0 = nx * 128;

    const u16* arow[4];
    const u16* brow[4];
#pragma unroll
    for (int i = 0; i < 4; ++i) {
        int r = (wv * 4 + i) * 8 + lrow;     // 0..127
        if (gather) {
            int tok = gidx[e * CPAD + m0 + r];
            arow[i] = (tok < NTOK) ? (AbaseE + (long)tok * DDIM) : zrow;
        } else {
            arow[i] = Ab + (long)(m0 + r) * DDIM;
        }
        brow[i] = Bb + (long)(n0 + r) * DDIM;
    }
    f32x4 acc[4][4];
#pragma unroll
    for (int a = 0; a < 4; ++a)
#pragma unroll
        for (int b = 0; b < 4; ++b) { f32x4 z = {0.f, 0.f, 0.f, 0.f}; acc[a][b] = z; }

    int wm = (wv >> 1) * 64, wn = (wv & 1) * 64;
    int rl = lane & 15, quad = lane >> 4;

    for (int k0 = 0; k0 < 1024; k0 += 64) {
#pragma unroll
        for (int i = 0; i < 4; ++i) {
            gl2lds16(arow[i] + k0 + kgs * 8, &ldsA[(wv * 4 + i) * 512]);
            gl2lds16(brow[i] + k0 + kgs * 8, &ldsB[(wv * 4 + i) * 512]);
        }
        __syncthreads();   // drains vmcnt -> staged tile visible
#pragma unroll
        for (int ks = 0; ks < 2; ++ks) {
            int kg = ks * 4 + quad;
            bf16x8 af[4], bf[4];
#pragma unroll
            for (int mi = 0; mi < 4; ++mi) {
                int row = wm + mi * 16 + rl;
                af[mi] = *(const bf16x8*)&ldsA[row * 64 + (kg ^ (row & 7)) * 8];
            }
#pragma unroll
            for (int ni = 0; ni < 4; ++ni) {
                int row = wn + ni * 16 + rl;
                bf[ni] = *(const bf16x8*)&ldsB[row * 64 + (kg ^ (row & 7)) * 8];
            }
#pragma unroll
            for (int mi = 0; mi < 4; ++mi)
#pragma unroll
                for (int ni = 0; ni < 4; ++ni)
                    acc[mi][ni] = __builtin_amdgcn_mfma_f32_16x16x32_bf16(
                        af[mi], bf[ni], acc[mi][ni], 0, 0, 0);
        }
        __syncthreads();   // all reads done before next tile overwrites
    }
    // epilogue: C/D layout col = lane&15, row = quad*4 + reg
#pragma unroll
    for (int ni = 0; ni < 4; ++ni) {
        int col = n0 + wn + ni * 16 + rl;
        float bv = bias[col];
#pragma unroll
        for (int mi = 0; mi < 4; ++mi) {
            int rowb = m0 + wm + mi * 16 + quad * 4;
#pragma unroll
            for (int r = 0; r < 4; ++r) {
                float v = acc[mi][ni][r] + bv;
                if constexpr (MODE_H) v = v > 0.f ? v : 0.f;
                outp[(long)(rowb + r) * DDIM + col] = f2bf(v);
            }
        }
    }
}

// ---------------- combine: out = Xs + g0*OutE[s0] + g1*OutE[s1] ----------------
__global__ __launch_bounds__(256) void k_combine(
    const u16* __restrict__ Xs, const u16* __restrict__ OutE,
    const int* __restrict__ ts0, const int* __restrict__ ts1,
    const float* __restrict__ p0, const float* __restrict__ p1,
    float* __restrict__ out) {
    int b = blockIdx.x;
    int d = threadIdx.x * 4;
    long base = (long)b * DDIM + d;
    ushort4 xs4 = *(const ushort4*)(Xs + base);
    float r0 = bf2f(xs4.x), r1 = bf2f(xs4.y), r2 = bf2f(xs4.z), r3 = bf2f(xs4.w);
    int s0 = ts0[b], s1 = ts1[b];
    if (s0 >= 0) {
        float g = p0[b];
        ushort4 o4 = *(const ushort4*)(OutE + (long)s0 * DDIM + d);
        r0 += g * bf2f(o4.x); r1 += g * bf2f(o4.y); r2 += g * bf2f(o4.z); r3 += g * bf2f(o4.w);
    }
    if (s1 >= 0) {
        float g = p1[b];
        ushort4 o4 = *(const ushort4*)(OutE + (long)s1 * DDIM + d);
        r0 += g * bf2f(o4.x); r1 += g * bf2f(o4.y); r2 += g * bf2f(o4.z); r3 += g * bf2f(o4.w);
    }
    float4 w; w.x = r0; w.y = r1; w.z = r2; w.w = r3;
    *(float4*)(out + base) = w;
}

extern "C" void kernel_launch(void* const* d_in, const int* in_sizes, int n_in,
                              void* d_out, int out_size, void* d_ws, size_t ws_size,
                              hipStream_t stream) {
    const float* x    = (const float*)d_in[0];
    const float* noise= (const float*)d_in[1];
    const float* Wr   = (const float*)d_in[2];
    const float* br   = (const float*)d_in[3];
    const float* Wn   = (const float*)d_in[4];
    const float* bn   = (const float*)d_in[5];
    const float* W1   = (const float*)d_in[6];
    const float* b1   = (const float*)d_in[7];
    const float* W2   = (const float*)d_in[8];
    const float* b2   = (const float*)d_in[9];
    const float* Ws1  = (const float*)d_in[10];
    const float* bs1  = (const float*)d_in[11];
    const float* Ws2  = (const float*)d_in[12];
    const float* bs2  = (const float*)d_in[13];
    float* out = (float*)d_out;
    char* ws = (char*)d_ws;

    size_t off = 0;
    auto alloc = [&](size_t bytes) { size_t o = off; off += (bytes + 255) & ~(size_t)255; return o; };
    u16*  Wt   = (u16*)(ws + alloc(7ull * 1048576 * 2));
    u16*  Wst  = (u16*)(ws + alloc(1048576ull * 2));
    u16*  xb   = (u16*)(ws + alloc((size_t)NTOK * 1024 * 2));
    u16*  He   = (u16*)(ws + alloc((size_t)NEXP * CPAD * 1024 * 2));
    u16*  Hs   = (u16*)(ws + alloc((size_t)NTOK * 1024 * 2));
    u16*  OutE = (u16*)(ws + alloc((size_t)NEXP * CPAD * 1024 * 2));
    u16*  Xs   = (u16*)(ws + alloc((size_t)NTOK * 1024 * 2));
    int*  idx0 = (int*)(ws + alloc(NTOK * 4));
    int*  idx1 = (int*)(ws + alloc(NTOK * 4));
    float* p0  = (float*)(ws + alloc(NTOK * 4));
    float* p1  = (float*)(ws + alloc(NTOK * 4));
    int*  ts0  = (int*)(ws + alloc(NTOK * 4));
    int*  ts1  = (int*)(ws + alloc(NTOK * 4));
    int*  slot_token = (int*)(ws + alloc(NEXP * CPAD * 4));
    int*  cnt8  = (int*)(ws + alloc(7 * 1024 * 4));
    int*  base8 = (int*)(ws + alloc(7 * 1024 * 4));
    double* sum8 = (double*)(ws + alloc(7 * 1024 * 8));
    int*  cnt    = (int*)(ws + alloc(8 * 4));
    u16*  zrow   = (u16*)(ws + alloc(1024 * 2));
    size_t base_off = off;
    // optional separate phase-2 transpose buffers (removes mid-pipeline bubble)
    u16*  Wt2  = (u16*)(ws + alloc(7ull * 1048576 * 2));
    u16*  Wst2 = (u16*)(ws + alloc(1048576ull * 2));

    if (base_off > ws_size) {
        k_zero<<<2048, 256, 0, stream>>>(out, (long)out_size);
        return;
    }
    bool sep = (off <= ws_size);
    if (!sep) { Wt2 = Wt; Wst2 = Wst; }
    int ntb = sep ? 1024 : 512;

    // prep: weight transposes + slot/zrow inits (x conversion now lives in k_router)
    k_prep<<<ntb + 74, 256, 0, stream>>>(
        slot_token, zrow, W1, Ws1, Wt, Wst, W2, Ws2, Wt2, Wst2, ntb);
    // fused router: logits + x->bf16 + top-2 tail + chunk-8 counts
    k_router<<<1024, 512, 0, stream>>>(
        x, Wr, Wn, br, bn, noise, xb, idx0, idx1, p0, p1, cnt8, sum8);
    k_scanbase<<<1, 896, 0, stream>>>(cnt8, sum8, base8, cnt, out);
    k_assign<<<32, 256, 0, stream>>>(idx0, idx1, base8, slot_token, ts0, ts1);

    // fused layer 1: experts (gather xb via slot_token) + shared, relu -> bf16 He/Hs
    k_gemm<true, true><<<TBLK, 256, 0, stream>>>(
        xb, xb, slot_token, zrow, Wt, Wst, b1, bs1, He, Hs, cnt);

    if (!sep)   // fallback: set1 transpose between the GEMMs
        k_transpose<<<512, 256, 0, stream>>>(W2, Ws2, Wt, Wst);

    // fused layer 2: -> bf16 OutE/Xs (+b2/bs2)
    k_gemm<false, false><<<TBLK, 256, 0, stream>>>(
        He, Hs, nullptr, zrow, Wt2, Wst2, b2, bs2, OutE, Xs, cnt);

    k_combine<<<NTOK, 256, 0, stream>>>(Xs, OutE, ts0, ts1, p0, p1, out);
    (void)in_sizes; (void)n_in; (void)out_size;
}